// Round 2
// baseline (218.938 us; speedup 1.0000x reference)
//
#include <hip/hip_runtime.h>
#include <stdint.h>
#include <math.h>

#define TPB 1024
#define NB1 2048          // level-1 bins: top-11 bits of monotonic key
#define LCAND 2560        // per-half-row local candidate cap
#define CAND2 4096        // global candidate cap in K2
#define SURV_MAX 1024     // final survivors <= top_k <= 1024

// monotonic float -> uint key (ascending key == ascending float)
__device__ __forceinline__ unsigned fkey(float f) {
    unsigned u = __float_as_uint(f);
    return (u & 0x80000000u) ? ~u : (u | 0x80000000u);
}
__device__ __forceinline__ float funkey(unsigned k) {
    unsigned u = (k & 0x80000000u) ? (k ^ 0x80000000u) : ~k;
    return __uint_as_float(u);
}

// ============================ K1 ============================
// grid = 2*B. Block (b, s) handles half-row [s*Vh, s*Vh+len).
// Produces: softmax partials (m,s), raw 2048-bin histogram, local candidate
// list (all elems >= local top-K threshold bin; superset of this block's
// share of the global top-K).
__global__ __launch_bounds__(TPB)
void k1_scan(const float* __restrict__ logits,
             const float* __restrict__ temps,
             const int* __restrict__ top_ks,
             float* __restrict__ ws_ms,            // [B][2][2]
             unsigned* __restrict__ ws_hist,       // [B][2][NB1]
             unsigned* __restrict__ ws_cnt,        // [B][2]
             unsigned long long* __restrict__ ws_cand, // [B][2][LCAND]
             int V, int Vh)
{
    const int blk = blockIdx.x;
    const int b = blk >> 1, s = blk & 1;
    const int tid = threadIdx.x;
    const int start = s * Vh;
    const int len = min(Vh, V - start);
    const float* __restrict__ row = logits + (size_t)b * V + start;
    const float invT = 1.0f / temps[b];
    int K = top_ks[b];
    if (K < 1) K = 1;
    if (K > 1024) K = 1024;

    __shared__ unsigned hist[NB1];
    __shared__ float sm[TPB], ss[TPB];
    __shared__ unsigned cnt;
    __shared__ int b1loc;

    for (int i = tid; i < NB1; i += TPB) hist[i] = 0;
    if (tid == 0) cnt = 0;
    __syncthreads();

    const int L4 = len >> 2;
    const float4* __restrict__ row4 = (const float4*)row;

    float m = -INFINITY, ssum = 0.0f;
    for (int i = tid; i < L4; i += TPB) {
        float4 v = row4[i];
        float vv[4] = {v.x, v.y, v.z, v.w};
        #pragma unroll
        for (int j = 0; j < 4; ++j) {
            float lv = vv[j];
            atomicAdd(&hist[fkey(lv) >> 21], 1u);
            float x = lv * invT;
            if (x > m) { ssum = ssum * expf(m - x) + 1.0f; m = x; }
            else       { ssum += expf(x - m); }
        }
    }
    for (int i = (L4 << 2) + tid; i < len; i += TPB) {
        float lv = row[i];
        atomicAdd(&hist[fkey(lv) >> 21], 1u);
        float x = lv * invT;
        if (x > m) { ssum = ssum * expf(m - x) + 1.0f; m = x; }
        else       { ssum += expf(x - m); }
    }
    sm[tid] = m; ss[tid] = ssum;
    __syncthreads();
    for (int d = TPB >> 1; d > 0; d >>= 1) {
        if (tid < d) {
            float m1 = sm[tid], s1 = ss[tid];
            float m2 = sm[tid + d], s2 = ss[tid + d];
            float mm = fmaxf(m1, m2);
            float t1 = (s1 > 0.0f) ? s1 * expf(m1 - mm) : 0.0f;
            float t2 = (s2 > 0.0f) ? s2 * expf(m2 - mm) : 0.0f;
            ss[tid] = t1 + t2;
            sm[tid] = mm;
        }
        __syncthreads();
    }
    if (tid == 0) {
        ws_ms[(size_t)(b * 2 + s) * 2 + 0] = sm[0];
        ws_ms[(size_t)(b * 2 + s) * 2 + 1] = ss[0];
    }

    // write raw histogram for K2 (all atomics done: barrier above)
    unsigned* gh = ws_hist + (size_t)(b * 2 + s) * NB1;
    for (int i = tid; i < NB1; i += TPB) gh[i] = hist[i];

    // in-place suffix sum: hist[i] = #keys with bin >= i
    for (int d = 1; d < NB1; d <<= 1) {
        unsigned a0 = (tid + d < NB1) ? hist[tid + d] : 0u;
        int e1 = tid + TPB;
        unsigned a1 = (e1 + d < NB1) ? hist[e1 + d] : 0u;
        __syncthreads();
        hist[tid] += a0;
        hist[e1]  += a1;
        __syncthreads();
    }
    const unsigned Ku = (unsigned)K;
    for (int e = tid; e < NB1; e += TPB) {
        unsigned Se = hist[e];
        unsigned Sn = (e + 1 < NB1) ? hist[e + 1] : 0u;
        if (Se >= Ku && (e + 1 >= NB1 || Sn < Ku)) b1loc = e;
    }
    __syncthreads();
    const unsigned Tloc = (unsigned)b1loc << 21;

    // gather local candidates (chunk is L2-resident)
    unsigned long long* gc = ws_cand + (size_t)(b * 2 + s) * LCAND;
    for (int i = tid; i < L4; i += TPB) {
        float4 v = row4[i];
        float vv[4] = {v.x, v.y, v.z, v.w};
        int base = start + (i << 2);
        #pragma unroll
        for (int j = 0; j < 4; ++j) {
            unsigned k = fkey(vv[j]);
            if (k >= Tloc) {
                unsigned pos = atomicAdd(&cnt, 1u);
                if (pos < LCAND)
                    gc[pos] = ((unsigned long long)k << 32) |
                              (unsigned long long)(~(unsigned)(base + j));
            }
        }
    }
    for (int i = (L4 << 2) + tid; i < len; i += TPB) {
        unsigned k = fkey(row[i]);
        if (k >= Tloc) {
            unsigned pos = atomicAdd(&cnt, 1u);
            if (pos < LCAND)
                gc[pos] = ((unsigned long long)k << 32) |
                          (unsigned long long)(~(unsigned)(start + i));
        }
    }
    __syncthreads();
    if (tid == 0) ws_cnt[b * 2 + s] = (cnt < LCAND) ? cnt : LCAND;
}

// ============================ K2 ============================
// grid = B. Combine partials, find global threshold, filter candidate union,
// sort, apply prefix masks, sample, emit token + survivor list.
__global__ __launch_bounds__(TPB)
void k2_sample(const float* __restrict__ temps,
               const int* __restrict__ top_ks,
               const float* __restrict__ top_ps,
               const float* __restrict__ min_ps,
               const float* __restrict__ uvec,
               const float* __restrict__ ws_ms,
               const unsigned* __restrict__ ws_hist,
               const unsigned* __restrict__ ws_cnt,
               const unsigned long long* __restrict__ ws_cand,
               float* __restrict__ out_tok,
               unsigned* __restrict__ ws_nf,
               uint2* __restrict__ ws_surv)
{
    const int b = blockIdx.x;
    const int tid = threadIdx.x;
    const float invT = 1.0f / temps[b];
    int K = top_ks[b];
    if (K < 1) K = 1;
    if (K > 1024) K = 1024;
    const float top_p = top_ps[b];
    const float min_p = min_ps[b];
    const float uval  = uvec[b];

    // combine softmax partials
    float m0 = ws_ms[(size_t)b * 4 + 0], s0 = ws_ms[(size_t)b * 4 + 1];
    float m1 = ws_ms[(size_t)b * 4 + 2], s1 = ws_ms[(size_t)b * 4 + 3];
    const float M = fmaxf(m0, m1);
    const float Z = ((s0 > 0.0f) ? s0 * expf(m0 - M) : 0.0f) +
                    ((s1 > 0.0f) ? s1 * expf(m1 - M) : 0.0f);

    __shared__ unsigned hist[NB1];
    __shared__ unsigned long long cand[CAND2];
    __shared__ float sh_p[TPB], sh_c[TPB];
    __shared__ unsigned cnt;
    __shared__ int sh_b1, sh_np, sh_nf;

    const unsigned* h0 = ws_hist + (size_t)(b * 2 + 0) * NB1;
    const unsigned* h1 = ws_hist + (size_t)(b * 2 + 1) * NB1;
    for (int i = tid; i < NB1; i += TPB) hist[i] = h0[i] + h1[i];
    if (tid == 0) cnt = 0;
    __syncthreads();

    for (int d = 1; d < NB1; d <<= 1) {
        unsigned a0 = (tid + d < NB1) ? hist[tid + d] : 0u;
        int e1 = tid + TPB;
        unsigned a1 = (e1 + d < NB1) ? hist[e1 + d] : 0u;
        __syncthreads();
        hist[tid] += a0;
        hist[e1]  += a1;
        __syncthreads();
    }
    const unsigned Ku = (unsigned)K;
    for (int e = tid; e < NB1; e += TPB) {
        unsigned Se = hist[e];
        unsigned Sn = (e + 1 < NB1) ? hist[e + 1] : 0u;
        if (Se >= Ku && (e + 1 >= NB1 || Sn < Ku)) sh_b1 = e;
    }
    __syncthreads();
    const unsigned Tkey = (unsigned)sh_b1 << 21;

    // filter candidate union by global threshold
    #pragma unroll
    for (int s = 0; s < 2; ++s) {
        int n = (int)ws_cnt[b * 2 + s];
        const unsigned long long* gc = ws_cand + (size_t)(b * 2 + s) * LCAND;
        for (int i = tid; i < n; i += TPB) {
            unsigned long long e = gc[i];
            if ((unsigned)(e >> 32) >= Tkey) {
                unsigned pos = atomicAdd(&cnt, 1u);
                if (pos < CAND2) cand[pos] = e;
            }
        }
    }
    __syncthreads();
    int count = (cnt < (unsigned)CAND2) ? (int)cnt : CAND2;
    if (K > count) K = count;

    // bitonic sort desc by (key desc, idx asc)  [~idx in low bits]
    int n_sort = 1;
    while (n_sort < count) n_sort <<= 1;
    for (int i = tid; i < n_sort; i += TPB)
        if (i >= count) cand[i] = 0ull;
    __syncthreads();
    for (int kk = 2; kk <= n_sort; kk <<= 1) {
        for (int j = kk >> 1; j > 0; j >>= 1) {
            for (int i = tid; i < n_sort; i += TPB) {
                int ixj = i ^ j;
                if (ixj > i) {
                    unsigned long long a = cand[i];
                    unsigned long long c = cand[ixj];
                    bool up = (i & kk) == 0;
                    if (up ? (a < c) : (a > c)) { cand[i] = c; cand[ixj] = a; }
                }
            }
            __syncthreads();
        }
    }

    // probs for top-K prefix, inclusive cumsum
    float pv = 0.0f;
    if (tid < K) {
        unsigned k = (unsigned)(cand[tid] >> 32);
        float x = funkey(k) * invT;
        pv = expf(x - M) / Z;
    }
    sh_p[tid] = pv;
    sh_c[tid] = pv;
    __syncthreads();
    for (int d = 1; d < TPB; d <<= 1) {
        float add = (tid >= d) ? sh_c[tid - d] : 0.0f;
        __syncthreads();
        sh_c[tid] += add;
        __syncthreads();
    }

    if (tid == 0) sh_np = K;
    __syncthreads();
    if (tid < K) {
        float excl = sh_c[tid] - sh_p[tid];   // cumsum BEFORE masking, exclusive
        if (excl > top_p) atomicMin(&sh_np, tid);
    }
    __syncthreads();
    int n1 = sh_np;
    float thr = sh_p[0] * min_p;
    if (tid == 0) sh_nf = n1;
    __syncthreads();
    if (tid < n1 && sh_p[tid] < thr) atomicMin(&sh_nf, tid);
    __syncthreads();
    int nf = sh_nf;                            // >= 1
    float total = sh_c[nf - 1];

    int pred = (tid < nf) && ((sh_c[tid] / total) < uval);
    int rank = __syncthreads_count(pred);
    if (rank > nf - 1) rank = nf - 1;
    if (rank < 0) rank = 0;
    if (tid == 0) {
        unsigned idx = ~(unsigned)(cand[rank] & 0xFFFFFFFFull);
        out_tok[b] = (float)idx;
        ws_nf[b] = (unsigned)nf;
    }
    if (tid < nf) {
        unsigned idx = ~(unsigned)(cand[tid] & 0xFFFFFFFFull);
        uint2 e; e.x = idx; e.y = __float_as_uint(sh_p[tid] / total);
        ws_surv[(size_t)b * SURV_MAX + tid] = e;
    }
}

// ============================ K3 ============================
// grid = 4*B. Zero a chunk in LDS, scatter survivors, stream out.
__global__ __launch_bounds__(TPB)
void k3_scatter(const unsigned* __restrict__ ws_nf,
                const uint2* __restrict__ ws_surv,
                float* __restrict__ out_probs,
                int V, int chlen)
{
    const int blk = blockIdx.x;
    const int b = blk >> 2, c = blk & 3;
    const int tid = threadIdx.x;
    const int start = c * chlen;
    const int len = min(chlen, V - start);
    if (len <= 0) return;

    __shared__ float buf[32768];
    float4* buf4 = (float4*)buf;
    float4 z4; z4.x = z4.y = z4.z = z4.w = 0.0f;
    for (int i = tid; i < 32768 / 4; i += TPB) buf4[i] = z4;
    __syncthreads();

    const int nf = (int)ws_nf[b];
    const uint2* sv = ws_surv + (size_t)b * SURV_MAX;
    for (int i = tid; i < nf; i += TPB) {
        uint2 e = sv[i];
        int idx = (int)e.x;
        if (idx >= start && idx < start + len)
            buf[idx - start] = __uint_as_float(e.y);
    }
    __syncthreads();

    float* orow = out_probs + (size_t)b * V + start;
    float4* orow4 = (float4*)orow;
    const int L4 = len >> 2;
    for (int i = tid; i < L4; i += TPB) orow4[i] = buf4[i];
    for (int i = (L4 << 2) + tid; i < len; i += TPB) orow[i] = buf[i];
}

extern "C" void kernel_launch(void* const* d_in, const int* in_sizes, int n_in,
                              void* d_out, int out_size, void* d_ws, size_t ws_size,
                              hipStream_t stream) {
    const float* logits = (const float*)d_in[0];
    const float* temps  = (const float*)d_in[1];
    const int*   top_ks = (const int*)d_in[2];
    const float* top_ps = (const float*)d_in[3];
    const float* min_ps = (const float*)d_in[4];
    const float* u      = (const float*)d_in[5];
    const int B = in_sizes[1];
    const int V = in_sizes[0] / B;
    float* out_tok   = (float*)d_out;
    float* out_probs = out_tok + B;

    // half-row length (float4-aligned), quarter-row chunk (<= 32768)
    int Vh = (((V + 1) / 2) + 3) & ~3;
    int chlen = (((V + 3) / 4) + 3) & ~3;

    // workspace layout (256 B-aligned regions)
    char* ws = (char*)d_ws;
    size_t off = 0;
    auto take = [&](size_t bytes) { char* p = ws + off; off = (off + bytes + 255) & ~(size_t)255; return p; };
    float*              ws_ms   = (float*)take((size_t)B * 4 * sizeof(float));
    unsigned*           ws_hist = (unsigned*)take((size_t)B * 2 * NB1 * sizeof(unsigned));
    unsigned*           ws_cnt  = (unsigned*)take((size_t)B * 2 * sizeof(unsigned));
    unsigned long long* ws_cand = (unsigned long long*)take((size_t)B * 2 * LCAND * sizeof(unsigned long long));
    unsigned*           ws_nf   = (unsigned*)take((size_t)B * sizeof(unsigned));
    uint2*              ws_surv = (uint2*)take((size_t)B * SURV_MAX * sizeof(uint2));
    (void)ws_size;

    k1_scan<<<dim3(2 * B), dim3(TPB), 0, stream>>>(
        logits, temps, top_ks, ws_ms, ws_hist, ws_cnt, ws_cand, V, Vh);
    k2_sample<<<dim3(B), dim3(TPB), 0, stream>>>(
        temps, top_ks, top_ps, min_ps, u, ws_ms, ws_hist, ws_cnt, ws_cand,
        out_tok, ws_nf, ws_surv);
    k3_scatter<<<dim3(4 * B), dim3(TPB), 0, stream>>>(
        ws_nf, ws_surv, out_probs, V, chlen);
}

// Round 3
// 193.365 us; speedup vs baseline: 1.1322x; 1.1322x over previous
//
#include <hip/hip_runtime.h>
#include <stdint.h>
#include <math.h>

#define TPB 1024
#define NB1 2048          // histogram bins (11 bits of monotonic key)
#define SPLIT 4           // row split for K1
#define LCAND 1536        // per-quarter-row candidate cap
#define CAND2 2048        // post-refine candidate cap in K2
#define SURV_MAX 1024
#define DELTA_X 5.0f      // histogram pre-filter: only x >= M - DELTA_X (exact w/ fallback)

// monotonic float -> uint key (ascending key == ascending float)
__device__ __forceinline__ unsigned fkey(float f) {
    unsigned u = __float_as_uint(f);
    return (u & 0x80000000u) ? ~u : (u | 0x80000000u);
}
__device__ __forceinline__ float funkey(unsigned k) {
    unsigned u = (k & 0x80000000u) ? (k ^ 0x80000000u) : ~k;
    return __uint_as_float(u);
}

// in-place suffix sum of h[0..NB1), shuffle-based (3 internal barriers).
// wscr: shared scratch >= 32 unsigned.
__device__ __forceinline__ void suffix_scan_2048(unsigned* h, unsigned* wscr, int tid)
{
    const int lane = tid & 63, w = tid >> 6;
    const int i0 = 2047 - 2 * tid;   // g-index 2t  (reversed -> prefix == suffix)
    const int i1 = 2046 - 2 * tid;   // g-index 2t+1
    unsigned a = h[i0], b = h[i1];
    unsigned s = a + b;
    unsigned inc = s;
    #pragma unroll
    for (int d = 1; d < 64; d <<= 1) { unsigned o = __shfl_up(inc, d); if (lane >= d) inc += o; }
    if (lane == 63) wscr[w] = inc;
    __syncthreads();
    if (w == 0) {
        unsigned v = (lane < 16) ? wscr[lane] : 0u;
        unsigned vi = v;
        #pragma unroll
        for (int d = 1; d < 16; d <<= 1) { unsigned o = __shfl_up(vi, d); if (lane >= d) vi += o; }
        if (lane < 16) wscr[16 + lane] = vi - v;   // exclusive wave offsets
    }
    __syncthreads();
    unsigned off = wscr[16 + w] + (inc - s);
    h[i0] = off + a;
    h[i1] = off + a + b;
    __syncthreads();
}

// ============================ K1 ============================
// grid = SPLIT*B. Block (b,s) owns [s*Vq, s*Vq+len).
__global__ __launch_bounds__(TPB)
void k1_scan(const float* __restrict__ logits,
             const float* __restrict__ temps,
             const int* __restrict__ top_ks,
             float* __restrict__ ws_ms,                // [B][SPLIT][2] = {y-max, Z}
             unsigned* __restrict__ ws_cnt,            // [B][SPLIT]
             unsigned long long* __restrict__ ws_cand, // [B][SPLIT][LCAND]
             int V, int Vq)
{
    const int blk = blockIdx.x;
    const int b = blk / SPLIT, s = blk % SPLIT;
    const int tid = threadIdx.x, lane = tid & 63, w = tid >> 6;
    const int start = s * Vq;
    const int len = min(Vq, V - start);
    const int slot = b * SPLIT + s;
    const float invT = 1.0f / temps[b];
    int K = top_ks[b];
    if (K < 1) K = 1;
    if (K > 1024) K = 1024;

    __shared__ unsigned hist[NB1];
    __shared__ unsigned wscr[32];
    __shared__ float fred[16];
    __shared__ float shM;
    __shared__ unsigned cnt;
    __shared__ int b1loc;

    if (len <= 0) {
        if (tid == 0) {
            ws_ms[2 * slot] = -INFINITY; ws_ms[2 * slot + 1] = 0.0f; ws_cnt[slot] = 0;
        }
        return;
    }

    for (int i = tid; i < NB1; i += TPB) hist[i] = 0;
    if (tid == 0) cnt = 0;

    const float* __restrict__ row = logits + (size_t)b * V + start;
    const float4* __restrict__ row4 = (const float4*)row;
    const int L4 = len >> 2;

    // ---- pass 1 (HBM): max only ----
    float m = -INFINITY;
    for (int i = tid; i < L4; i += TPB) {
        float4 v = row4[i];
        m = fmaxf(m, fmaxf(fmaxf(v.x, v.y), fmaxf(v.z, v.w)));
    }
    for (int i = (L4 << 2) + tid; i < len; i += TPB) m = fmaxf(m, row[i]);
    #pragma unroll
    for (int d = 32; d > 0; d >>= 1) m = fmaxf(m, __shfl_down(m, d));
    if (lane == 0) fred[w] = m;
    __syncthreads();
    if (tid == 0) {
        float mm = fred[0];
        for (int j = 1; j < 16; ++j) mm = fmaxf(mm, fred[j]);
        shM = mm;
    }
    __syncthreads();
    const float Mx = shM;
    const unsigned cutkey = fkey(Mx - DELTA_X);
    const float c = invT * 1.44269504088896f;   // log2(e)/T

    // ---- pass 2 (cache): Z-sum (independent exp2f) + filtered histogram ----
    float z = 0.0f; unsigned pc = 0;
    for (int i = tid; i < L4; i += TPB) {
        float4 v = row4[i];
        float vv[4] = {v.x, v.y, v.z, v.w};
        #pragma unroll
        for (int j = 0; j < 4; ++j) {
            float lv = vv[j];
            z += exp2f((lv - Mx) * c);
            unsigned k = fkey(lv);
            if (k >= cutkey) { atomicAdd(&hist[k >> 21], 1u); pc++; }
        }
    }
    for (int i = (L4 << 2) + tid; i < len; i += TPB) {
        float lv = row[i];
        z += exp2f((lv - Mx) * c);
        unsigned k = fkey(lv);
        if (k >= cutkey) { atomicAdd(&hist[k >> 21], 1u); pc++; }
    }
    #pragma unroll
    for (int d = 32; d > 0; d >>= 1) { z += __shfl_down(z, d); pc += __shfl_down(pc, d); }
    if (lane == 0) { fred[w] = z; atomicAdd(&cnt, pc); }
    __syncthreads();
    if (tid == 0) {
        float zz = 0.0f;
        for (int j = 0; j < 16; ++j) zz += fred[j];
        ws_ms[2 * slot]     = Mx * invT;   // y-space max
        ws_ms[2 * slot + 1] = zz;          // sum exp(y - ymax)
    }
    const unsigned nAbove = cnt;
    __syncthreads();
    if (tid == 0) cnt = 0;                 // reused as gather counter (ordered by scan barriers)

    const unsigned Ku = (unsigned)K;
    unsigned Ksearch = Ku;
    if (nAbove < Ku) {                     // exact fallback (not taken for bench data)
        Ksearch = (Ku < (unsigned)len) ? Ku : (unsigned)len;
        for (int i = tid; i < NB1; i += TPB) hist[i] = 0;
        __syncthreads();
        for (int i = tid; i < len; i += TPB) atomicAdd(&hist[fkey(row[i]) >> 21], 1u);
        __syncthreads();
    }

    suffix_scan_2048(hist, wscr, tid);
    for (int e = tid; e < NB1; e += TPB) {
        unsigned Se = hist[e];
        unsigned Sn = (e < NB1 - 1) ? hist[e + 1] : 0u;
        if (Se >= Ksearch && Sn < Ksearch) b1loc = e;   // unique writer
    }
    __syncthreads();
    const unsigned Tloc = (unsigned)b1loc << 21;

    // ---- pass 3 (cache): gather local candidates ----
    unsigned long long* gc = ws_cand + (size_t)slot * LCAND;
    for (int i = tid; i < L4; i += TPB) {
        float4 v = row4[i];
        float vv[4] = {v.x, v.y, v.z, v.w};
        int base = start + (i << 2);
        #pragma unroll
        for (int j = 0; j < 4; ++j) {
            unsigned k = fkey(vv[j]);
            if (k >= Tloc) {
                unsigned pos = atomicAdd(&cnt, 1u);
                if (pos < LCAND)
                    gc[pos] = ((unsigned long long)k << 32) |
                              (unsigned long long)(~(unsigned)(base + j));
            }
        }
    }
    for (int i = (L4 << 2) + tid; i < len; i += TPB) {
        unsigned k = fkey(row[i]);
        if (k >= Tloc) {
            unsigned pos = atomicAdd(&cnt, 1u);
            if (pos < LCAND)
                gc[pos] = ((unsigned long long)k << 32) |
                          (unsigned long long)(~(unsigned)(start + i));
        }
    }
    __syncthreads();
    if (tid == 0) ws_cnt[slot] = (cnt < LCAND) ? cnt : LCAND;
}

// ============================ K2 ============================
// grid = B. Candidate-only threshold refine (exact above global L1 bin),
// rank-by-counting sort, prefix masks, sample.
__global__ __launch_bounds__(TPB)
void k2_sample(const float* __restrict__ temps,
               const int* __restrict__ top_ks,
               const float* __restrict__ top_ps,
               const float* __restrict__ min_ps,
               const float* __restrict__ uvec,
               const float* __restrict__ ws_ms,
               const unsigned* __restrict__ ws_cnt,
               const unsigned long long* __restrict__ ws_cand,
               float* __restrict__ out_tok,
               unsigned* __restrict__ ws_nf,
               uint2* __restrict__ ws_surv)
{
    const int b = blockIdx.x;
    const int tid = threadIdx.x, lane = tid & 63, w = tid >> 6;
    const float invT = 1.0f / temps[b];
    int K = top_ks[b];
    if (K < 1) K = 1;
    if (K > 1024) K = 1024;
    const float top_p = top_ps[b];
    const float min_p = min_ps[b];
    const float uval  = uvec[b];

    __shared__ unsigned hist[NB1];
    __shared__ unsigned wscr[32];
    __shared__ __align__(16) unsigned long long cand[CAND2];
    __shared__ float sh_p[TPB], sh_c[TPB];
    __shared__ float fws[32];
    __shared__ unsigned cnt;
    __shared__ int sh_b1, sh_b2, sh_np, sh_nf;
    __shared__ unsigned sh_cab;

    // combine softmax partials
    float M = -INFINITY;
    #pragma unroll
    for (int q = 0; q < SPLIT; ++q) M = fmaxf(M, ws_ms[(size_t)(b * SPLIT + q) * 2]);
    float Z = 0.0f;
    #pragma unroll
    for (int q = 0; q < SPLIT; ++q) {
        float mm = ws_ms[(size_t)(b * SPLIT + q) * 2];
        float zz = ws_ms[(size_t)(b * SPLIT + q) * 2 + 1];
        if (zz > 0.0f) Z += zz * expf(mm - M);
    }
    int nlist[SPLIT];
    #pragma unroll
    for (int q = 0; q < SPLIT; ++q) nlist[q] = (int)ws_cnt[b * SPLIT + q];

    for (int i = tid; i < NB1; i += TPB) hist[i] = 0;
    for (int i = tid; i < CAND2; i += TPB) cand[i] = 0ull;
    if (tid == 0) cnt = 0;
    __syncthreads();

    // L1 histogram over candidate union (exact for bins >= global b1)
    #pragma unroll
    for (int q = 0; q < SPLIT; ++q) {
        const unsigned long long* gc = ws_cand + (size_t)(b * SPLIT + q) * LCAND;
        for (int i = tid; i < nlist[q]; i += TPB)
            atomicAdd(&hist[(unsigned)(gc[i] >> 32) >> 21], 1u);
    }
    __syncthreads();
    suffix_scan_2048(hist, wscr, tid);
    const unsigned Ku = (unsigned)K;
    for (int e = tid; e < NB1; e += TPB) {
        unsigned Se = hist[e];
        unsigned Sn = (e < NB1 - 1) ? hist[e + 1] : 0u;
        if (Se >= Ku && Sn < Ku) { sh_b1 = e; sh_cab = Sn; }
    }
    __syncthreads();
    const int b1 = sh_b1;
    const unsigned cab = sh_cab;          // exact count strictly above bin b1
    for (int i = tid; i < NB1; i += TPB) hist[i] = 0;
    __syncthreads();

    // L2 histogram (bits 20:10) of candidates inside bin b1
    #pragma unroll
    for (int q = 0; q < SPLIT; ++q) {
        const unsigned long long* gc = ws_cand + (size_t)(b * SPLIT + q) * LCAND;
        for (int i = tid; i < nlist[q]; i += TPB) {
            unsigned k = (unsigned)(gc[i] >> 32);
            if ((int)(k >> 21) == b1) atomicAdd(&hist[(k >> 10) & (NB1 - 1)], 1u);
        }
    }
    __syncthreads();
    suffix_scan_2048(hist, wscr, tid);
    for (int e = tid; e < NB1; e += TPB) {
        unsigned Se = cab + hist[e];
        unsigned Sn = cab + ((e < NB1 - 1) ? hist[e + 1] : 0u);
        if (Se >= Ku && Sn < Ku) sh_b2 = e;
    }
    __syncthreads();
    const unsigned Tkey = ((unsigned)b1 << 21) | ((unsigned)sh_b2 << 10);

    // compact candidates >= Tkey (count ~ K + epsilon)
    #pragma unroll
    for (int q = 0; q < SPLIT; ++q) {
        const unsigned long long* gc = ws_cand + (size_t)(b * SPLIT + q) * LCAND;
        for (int i = tid; i < nlist[q]; i += TPB) {
            unsigned long long e = gc[i];
            if ((unsigned)(e >> 32) >= Tkey) {
                unsigned pos = atomicAdd(&cnt, 1u);
                if (pos < CAND2) cand[pos] = e;
            }
        }
    }
    __syncthreads();
    int count = (cnt < (unsigned)CAND2) ? (int)cnt : CAND2;
    if (K > count) K = count;

    // rank-by-counting sort (desc by packed (key, ~idx)); zero-pad is neutral
    unsigned long long v0 = (tid < count) ? cand[tid] : 0ull;
    const int idx1 = tid + TPB;
    unsigned long long v1 = (idx1 < count) ? cand[idx1] : 0ull;
    int r0 = 0, r1 = 0;
    const ulonglong2* c2 = (const ulonglong2*)cand;
    const int n4 = (count + 3) >> 2;
    for (int q = 0; q < n4; ++q) {
        ulonglong2 e0 = c2[2 * q], e1 = c2[2 * q + 1];
        r0 += (e0.x > v0) + (e0.y > v0) + (e1.x > v0) + (e1.y > v0);
        r1 += (e0.x > v1) + (e0.y > v1) + (e1.x > v1) + (e1.y > v1);
    }
    __syncthreads();
    if (tid  < count) cand[r0] = v0;
    if (idx1 < count) cand[r1] = v1;
    __syncthreads();

    // probs for top-K prefix
    float pv = 0.0f;
    if (tid < K) {
        unsigned k = (unsigned)(cand[tid] >> 32);
        pv = expf(funkey(k) * invT - M) / Z;
    }
    // shuffle-based inclusive prefix sum over 1024 threads
    float inc = pv;
    #pragma unroll
    for (int d = 1; d < 64; d <<= 1) { float o = __shfl_up(inc, d); if (lane >= d) inc += o; }
    if (lane == 63) fws[w] = inc;
    __syncthreads();
    if (w == 0) {
        float v = (lane < 16) ? fws[lane] : 0.0f;
        float vi = v;
        #pragma unroll
        for (int d = 1; d < 16; d <<= 1) { float o = __shfl_up(vi, d); if (lane >= d) vi += o; }
        if (lane < 16) fws[16 + lane] = vi - v;
    }
    __syncthreads();
    float cum = inc + fws[16 + w];
    sh_p[tid] = pv;
    sh_c[tid] = cum;
    if (tid == 0) sh_np = K;
    __syncthreads();

    // top-p (exclusive cumsum computed BEFORE masking, as reference)
    if (tid < K) {
        float excl = cum - pv;
        if (excl > top_p) atomicMin(&sh_np, tid);
    }
    __syncthreads();
    int n1 = sh_np;
    float thr = sh_p[0] * min_p;
    if (tid == 0) sh_nf = n1;
    __syncthreads();
    if (tid < n1 && sh_p[tid] < thr) atomicMin(&sh_nf, tid);
    __syncthreads();
    int nf = sh_nf;                        // >= 1
    float total = sh_c[nf - 1];

    int pred = (tid < nf) && ((sh_c[tid] / total) < uval);
    int rank = __syncthreads_count(pred);
    if (rank > nf - 1) rank = nf - 1;
    if (rank < 0) rank = 0;
    if (tid == 0) {
        unsigned idx = ~(unsigned)(cand[rank] & 0xFFFFFFFFull);
        out_tok[b] = (float)idx;
        ws_nf[b] = (unsigned)nf;
    }
    if (tid < nf) {
        unsigned idx = ~(unsigned)(cand[tid] & 0xFFFFFFFFull);
        uint2 e; e.x = idx; e.y = __float_as_uint(sh_p[tid] / total);
        ws_surv[(size_t)b * SURV_MAX + tid] = e;
    }
}

// ============================ K3 ============================
// grid = 4*B. Zero an LDS chunk, scatter survivors, stream out.
__global__ __launch_bounds__(TPB)
void k3_scatter(const unsigned* __restrict__ ws_nf,
                const uint2* __restrict__ ws_surv,
                float* __restrict__ out_probs,
                int V, int chlen)
{
    const int blk = blockIdx.x;
    const int b = blk >> 2, c = blk & 3;
    const int tid = threadIdx.x;
    const int start = c * chlen;
    const int len = min(chlen, V - start);
    if (len <= 0) return;

    __shared__ float buf[32768];
    float4* buf4 = (float4*)buf;
    float4 z4; z4.x = z4.y = z4.z = z4.w = 0.0f;
    for (int i = tid; i < 32768 / 4; i += TPB) buf4[i] = z4;
    __syncthreads();

    const int nf = (int)ws_nf[b];
    const uint2* sv = ws_surv + (size_t)b * SURV_MAX;
    for (int i = tid; i < nf; i += TPB) {
        uint2 e = sv[i];
        int idx = (int)e.x;
        if (idx >= start && idx < start + len)
            buf[idx - start] = __uint_as_float(e.y);
    }
    __syncthreads();

    float* orow = out_probs + (size_t)b * V + start;
    float4* orow4 = (float4*)orow;
    const int L4 = len >> 2;
    for (int i = tid; i < L4; i += TPB) orow4[i] = buf4[i];
    for (int i = (L4 << 2) + tid; i < len; i += TPB) orow[i] = buf[i];
}

extern "C" void kernel_launch(void* const* d_in, const int* in_sizes, int n_in,
                              void* d_out, int out_size, void* d_ws, size_t ws_size,
                              hipStream_t stream) {
    const float* logits = (const float*)d_in[0];
    const float* temps  = (const float*)d_in[1];
    const int*   top_ks = (const int*)d_in[2];
    const float* top_ps = (const float*)d_in[3];
    const float* min_ps = (const float*)d_in[4];
    const float* u      = (const float*)d_in[5];
    const int B = in_sizes[1];
    const int V = in_sizes[0] / B;
    float* out_tok   = (float*)d_out;
    float* out_probs = out_tok + B;

    int Vq = (((V + SPLIT - 1) / SPLIT) + 3) & ~3;      // quarter-row, float4-aligned
    int chlen = (((V + 3) / 4) + 3) & ~3;               // K3 chunk <= 32768

    char* ws = (char*)d_ws;
    size_t off = 0;
    auto take = [&](size_t bytes) { char* p = ws + off; off = (off + bytes + 255) & ~(size_t)255; return p; };
    float*              ws_ms   = (float*)take((size_t)B * SPLIT * 2 * sizeof(float));
    unsigned*           ws_cnt  = (unsigned*)take((size_t)B * SPLIT * sizeof(unsigned));
    unsigned long long* ws_cand = (unsigned long long*)take((size_t)B * SPLIT * LCAND * sizeof(unsigned long long));
    unsigned*           ws_nf   = (unsigned*)take((size_t)B * sizeof(unsigned));
    uint2*              ws_surv = (uint2*)take((size_t)B * SURV_MAX * sizeof(uint2));
    (void)ws_size;

    k1_scan<<<dim3(SPLIT * B), dim3(TPB), 0, stream>>>(
        logits, temps, top_ks, ws_ms, ws_cnt, ws_cand, V, Vq);
    k2_sample<<<dim3(B), dim3(TPB), 0, stream>>>(
        temps, top_ks, top_ps, min_ps, u, ws_ms, ws_cnt, ws_cand,
        out_tok, ws_nf, ws_surv);
    k3_scatter<<<dim3(4 * B), dim3(TPB), 0, stream>>>(
        ws_nf, ws_surv, out_probs, V, chlen);
}

// Round 4
// 172.892 us; speedup vs baseline: 1.2663x; 1.1184x over previous
//
#include <hip/hip_runtime.h>
#include <stdint.h>
#include <math.h>

#define TPB 1024
#define NB 2048           // histogram bins (11-bit digits)
#define SPLIT 4           // row split for K1
#define LCAND 1536        // per-quarter-row candidate cap (observed ~1100 max)
#define CAND2 2048        // post-refine candidate cap in K2

typedef float vfloat4 __attribute__((ext_vector_type(4)));

// monotonic float -> uint key (ascending key == ascending float)
__device__ __forceinline__ unsigned fkey(float f) {
    unsigned u = __float_as_uint(f);
    return (u & 0x80000000u) ? ~u : (u | 0x80000000u);
}
__device__ __forceinline__ float funkey(unsigned k) {
    unsigned u = (k & 0x80000000u) ? (k ^ 0x80000000u) : ~k;
    return __uint_as_float(u);
}

// in-place suffix sum of h[0..NB), shuffle-based. Call with a barrier before;
// ends with a barrier.
__device__ __forceinline__ void suffix_scan_2048(unsigned* h, unsigned* wscr, int tid)
{
    const int lane = tid & 63, w = tid >> 6;
    const int i0 = 2047 - 2 * tid;
    const int i1 = 2046 - 2 * tid;
    unsigned a = h[i0], b = h[i1];
    unsigned s = a + b;
    unsigned inc = s;
    #pragma unroll
    for (int d = 1; d < 64; d <<= 1) { unsigned o = __shfl_up(inc, d); if (lane >= d) inc += o; }
    if (lane == 63) wscr[w] = inc;
    __syncthreads();
    if (w == 0) {
        unsigned v = (lane < 16) ? wscr[lane] : 0u;
        unsigned vi = v;
        #pragma unroll
        for (int d = 1; d < 16; d <<= 1) { unsigned o = __shfl_up(vi, d); if (lane >= d) vi += o; }
        if (lane < 16) wscr[16 + lane] = vi - v;
    }
    __syncthreads();
    unsigned off = wscr[16 + w] + (inc - s);
    h[i0] = off + a;
    h[i1] = off + a + b;
    __syncthreads();
}

// ============================ K1 ============================
// grid = SPLIT*B. One HBM pass: online softmax + 4-way sub-histogram +
// nontemporal zeroing of out_probs chunk. Then threshold + cache-hit gather.
__global__ __launch_bounds__(TPB)
void k1_scan(const float* __restrict__ logits,
             const float* __restrict__ temps,
             const int* __restrict__ top_ks,
             float* __restrict__ out_probs,            // zeroed here
             float* __restrict__ ws_ms,                // [B][SPLIT][2] = {y-max, Z}
             unsigned* __restrict__ ws_cnt,            // [B][SPLIT]
             unsigned long long* __restrict__ ws_cand, // [B][SPLIT][LCAND]
             int V, int Vq)
{
    const int blk = blockIdx.x;
    const int b = blk / SPLIT, s = blk % SPLIT;
    const int tid = threadIdx.x, lane = tid & 63, w = tid >> 6;
    const int start = s * Vq;
    const int len = min(Vq, V - start);
    const int slot = b * SPLIT + s;
    const float invT = 1.0f / temps[b];
    int K = top_ks[b];
    if (K < 1) K = 1;
    if (K > 1024) K = 1024;

    __shared__ unsigned sub[NB * 4];
    __shared__ unsigned hist[NB];
    __shared__ unsigned wscr[32];
    __shared__ float sm[TPB], ss[TPB];
    __shared__ unsigned cnt;
    __shared__ int b1loc;

    if (len <= 0) {
        if (tid == 0) {
            ws_ms[2 * slot] = -INFINITY; ws_ms[2 * slot + 1] = 0.0f; ws_cnt[slot] = 0;
        }
        return;
    }

    for (int i = tid; i < NB * 4; i += TPB) sub[i] = 0;
    if (tid == 0) cnt = 0;
    __syncthreads();

    const float* __restrict__ row = logits + (size_t)b * V + start;
    const vfloat4* __restrict__ row4 = (const vfloat4*)row;
    float* __restrict__ orow = out_probs + (size_t)b * V + start;
    vfloat4* __restrict__ orow4 = (vfloat4*)orow;
    const int L4 = len >> 2;
    const int c4 = tid & 3;
    const vfloat4 z4 = (vfloat4)0.0f;

    // ---- pass 1 (HBM): online softmax in y-space + histogram + zero out ----
    float m = -INFINITY, zsum = 0.0f;
    for (int i = tid; i < L4; i += TPB) {
        vfloat4 v = row4[i];
        __builtin_nontemporal_store(z4, &orow4[i]);
        #pragma unroll
        for (int j = 0; j < 4; ++j) {
            float lv = v[j];
            atomicAdd(&sub[((fkey(lv) >> 21) << 2) | c4], 1u);
            float y = lv * invT;
            if (y > m) { zsum = zsum * expf(m - y) + 1.0f; m = y; }
            else       { zsum += expf(y - m); }
        }
    }
    for (int i = (L4 << 2) + tid; i < len; i += TPB) {
        float lv = row[i];
        __builtin_nontemporal_store(0.0f, &orow[i]);
        atomicAdd(&sub[((fkey(lv) >> 21) << 2) | c4], 1u);
        float y = lv * invT;
        if (y > m) { zsum = zsum * expf(m - y) + 1.0f; m = y; }
        else       { zsum += expf(y - m); }
    }
    sm[tid] = m; ss[tid] = zsum;
    __syncthreads();
    for (int d = TPB >> 1; d > 0; d >>= 1) {
        if (tid < d) {
            float m1 = sm[tid], s1 = ss[tid];
            float m2 = sm[tid + d], s2 = ss[tid + d];
            float mm = fmaxf(m1, m2);
            float t1 = (s1 > 0.0f) ? s1 * expf(m1 - mm) : 0.0f;
            float t2 = (s2 > 0.0f) ? s2 * expf(m2 - mm) : 0.0f;
            ss[tid] = t1 + t2;
            sm[tid] = mm;
        }
        __syncthreads();
    }
    if (tid == 0) {
        ws_ms[2 * slot]     = sm[0];
        ws_ms[2 * slot + 1] = ss[0];
    }

    // merge sub-histograms, suffix-scan, local threshold
    for (int j = tid; j < NB; j += TPB)
        hist[j] = sub[4 * j] + sub[4 * j + 1] + sub[4 * j + 2] + sub[4 * j + 3];
    __syncthreads();
    suffix_scan_2048(hist, wscr, tid);
    const unsigned Ku = (unsigned)K;
    const unsigned Ksearch = (Ku < (unsigned)len) ? Ku : (unsigned)len;
    for (int e = tid; e < NB; e += TPB) {
        unsigned Se = hist[e];
        unsigned Sn = (e < NB - 1) ? hist[e + 1] : 0u;
        if (Se >= Ksearch && Sn < Ksearch) b1loc = e;   // unique writer
    }
    __syncthreads();
    const unsigned Tloc = (unsigned)b1loc << 21;

    // ---- pass 2 (L3-resident): gather local candidates ----
    unsigned long long* gc = ws_cand + (size_t)slot * LCAND;
    for (int i = tid; i < L4; i += TPB) {
        vfloat4 v = row4[i];
        int base = start + (i << 2);
        #pragma unroll
        for (int j = 0; j < 4; ++j) {
            unsigned k = fkey(v[j]);
            if (k >= Tloc) {
                unsigned pos = atomicAdd(&cnt, 1u);
                if (pos < LCAND)
                    gc[pos] = ((unsigned long long)k << 32) |
                              (unsigned long long)(~(unsigned)(base + j));
            }
        }
    }
    for (int i = (L4 << 2) + tid; i < len; i += TPB) {
        unsigned k = fkey(row[i]);
        if (k >= Tloc) {
            unsigned pos = atomicAdd(&cnt, 1u);
            if (pos < LCAND)
                gc[pos] = ((unsigned long long)k << 32) |
                          (unsigned long long)(~(unsigned)(start + i));
        }
    }
    __syncthreads();
    if (tid == 0) ws_cnt[slot] = (cnt < LCAND) ? cnt : LCAND;
}

// ============================ K2 ============================
// grid = B. 3-level exact threshold refine over candidate lists, compact
// (count ~ K), bitonic sort, prefix masks, sample, direct scatter.
__global__ __launch_bounds__(TPB)
void k2_sample(const float* __restrict__ temps,
               const int* __restrict__ top_ks,
               const float* __restrict__ top_ps,
               const float* __restrict__ min_ps,
               const float* __restrict__ uvec,
               const float* __restrict__ ws_ms,
               const unsigned* __restrict__ ws_cnt,
               const unsigned long long* __restrict__ ws_cand,
               float* __restrict__ out_tok,
               float* __restrict__ out_probs,
               int V)
{
    const int b = blockIdx.x;
    const int tid = threadIdx.x, lane = tid & 63, w = tid >> 6;
    const float invT = 1.0f / temps[b];
    int K = top_ks[b];
    if (K < 1) K = 1;
    if (K > 1024) K = 1024;
    const float top_p = top_ps[b];
    const float min_p = min_ps[b];
    const float uval  = uvec[b];

    __shared__ unsigned sub[NB * 4];
    __shared__ unsigned hist[NB];
    __shared__ unsigned wscr[32];
    __shared__ __align__(16) unsigned long long cand[CAND2];
    __shared__ float sh_p[TPB], sh_c[TPB];
    __shared__ float fws[32];
    __shared__ unsigned cnt;
    __shared__ int sh_b1, sh_b2, sh_b3, sh_np, sh_nf;
    __shared__ unsigned sh_cab1, sh_cab2;

    // combine softmax partials
    float M = -INFINITY;
    #pragma unroll
    for (int q = 0; q < SPLIT; ++q) M = fmaxf(M, ws_ms[(size_t)(b * SPLIT + q) * 2]);
    float Z = 0.0f;
    #pragma unroll
    for (int q = 0; q < SPLIT; ++q) {
        float mm = ws_ms[(size_t)(b * SPLIT + q) * 2];
        float zz = ws_ms[(size_t)(b * SPLIT + q) * 2 + 1];
        if (zz > 0.0f) Z += zz * expf(mm - M);
    }
    int nlist[SPLIT];
    #pragma unroll
    for (int q = 0; q < SPLIT; ++q) nlist[q] = (int)ws_cnt[b * SPLIT + q];
    const unsigned Ku = (unsigned)K;
    const int c4 = tid & 3;

    // ---------- level 1: bits 31:21 ----------
    for (int i = tid; i < NB * 4; i += TPB) sub[i] = 0;
    if (tid == 0) { cnt = 0; sh_b1 = 0; sh_b2 = 0; sh_b3 = 0; sh_cab1 = 0; sh_cab2 = 0; }
    __syncthreads();
    #pragma unroll
    for (int q = 0; q < SPLIT; ++q) {
        const unsigned long long* gc = ws_cand + (size_t)(b * SPLIT + q) * LCAND;
        for (int i = tid; i < nlist[q]; i += TPB)
            atomicAdd(&sub[(((unsigned)(gc[i] >> 32) >> 21) << 2) | c4], 1u);
    }
    __syncthreads();
    for (int j = tid; j < NB; j += TPB)
        hist[j] = sub[4 * j] + sub[4 * j + 1] + sub[4 * j + 2] + sub[4 * j + 3];
    __syncthreads();
    suffix_scan_2048(hist, wscr, tid);
    for (int e = tid; e < NB; e += TPB) {
        unsigned Se = hist[e];
        unsigned Sn = (e < NB - 1) ? hist[e + 1] : 0u;
        if (Se >= Ku && Sn < Ku) { sh_b1 = e; sh_cab1 = Sn; }
    }
    __syncthreads();
    const int b1 = sh_b1;
    const unsigned cab1 = sh_cab1;

    // ---------- level 2: bits 20:10 inside bin b1 ----------
    for (int i = tid; i < NB * 4; i += TPB) sub[i] = 0;
    __syncthreads();
    #pragma unroll
    for (int q = 0; q < SPLIT; ++q) {
        const unsigned long long* gc = ws_cand + (size_t)(b * SPLIT + q) * LCAND;
        for (int i = tid; i < nlist[q]; i += TPB) {
            unsigned k = (unsigned)(gc[i] >> 32);
            if ((int)(k >> 21) == b1)
                atomicAdd(&sub[(((k >> 10) & (NB - 1)) << 2) | c4], 1u);
        }
    }
    __syncthreads();
    for (int j = tid; j < NB; j += TPB)
        hist[j] = sub[4 * j] + sub[4 * j + 1] + sub[4 * j + 2] + sub[4 * j + 3];
    __syncthreads();
    suffix_scan_2048(hist, wscr, tid);
    for (int e = tid; e < NB; e += TPB) {
        unsigned Se = cab1 + hist[e];
        unsigned Sn = cab1 + ((e < NB - 1) ? hist[e + 1] : 0u);
        if (Se >= Ku && Sn < Ku) { sh_b2 = e; sh_cab2 = Sn; }
    }
    __syncthreads();
    const unsigned hi21 = ((unsigned)b1 << 11) | (unsigned)sh_b2;
    const unsigned cab2 = sh_cab2;

    // ---------- level 3: bits 9:0 inside (b1,b2) ----------
    for (int i = tid; i < NB * 4; i += TPB) sub[i] = 0;
    __syncthreads();
    #pragma unroll
    for (int q = 0; q < SPLIT; ++q) {
        const unsigned long long* gc = ws_cand + (size_t)(b * SPLIT + q) * LCAND;
        for (int i = tid; i < nlist[q]; i += TPB) {
            unsigned k = (unsigned)(gc[i] >> 32);
            if ((k >> 10) == hi21)
                atomicAdd(&sub[((k & 1023u) << 2) | c4], 1u);
        }
    }
    __syncthreads();
    for (int j = tid; j < NB; j += TPB)
        hist[j] = sub[4 * j] + sub[4 * j + 1] + sub[4 * j + 2] + sub[4 * j + 3];
    __syncthreads();
    suffix_scan_2048(hist, wscr, tid);
    for (int e = tid; e < 1024; e += TPB) {
        unsigned Se = cab2 + hist[e];
        unsigned Sn = cab2 + ((e < 1023) ? hist[e + 1] : 0u);
        if (Se >= Ku && Sn < Ku) sh_b3 = e;
    }
    __syncthreads();
    const unsigned Tkey = (hi21 << 10) | (unsigned)sh_b3;

    // ---------- compact candidates >= Tkey (count ~ K) ----------
    #pragma unroll
    for (int q = 0; q < SPLIT; ++q) {
        const unsigned long long* gc = ws_cand + (size_t)(b * SPLIT + q) * LCAND;
        for (int i = tid; i < nlist[q]; i += TPB) {
            unsigned long long e = gc[i];
            if ((unsigned)(e >> 32) >= Tkey) {
                unsigned pos = atomicAdd(&cnt, 1u);
                if (pos < CAND2) cand[pos] = e;
            }
        }
    }
    __syncthreads();
    int count = (cnt < (unsigned)CAND2) ? (int)cnt : CAND2;
    if (K > count) K = count;

    // ---------- bitonic sort desc by (key desc, idx asc) ----------
    int n_sort = 1;
    while (n_sort < count) n_sort <<= 1;
    for (int i = tid; i < n_sort; i += TPB)
        if (i >= count) cand[i] = 0ull;
    __syncthreads();
    for (int kk = 2; kk <= n_sort; kk <<= 1) {
        for (int j = kk >> 1; j > 0; j >>= 1) {
            for (int i = tid; i < n_sort; i += TPB) {
                int ixj = i ^ j;
                if (ixj > i) {
                    unsigned long long a = cand[i];
                    unsigned long long c = cand[ixj];
                    bool up = (i & kk) == 0;
                    if (up ? (a < c) : (a > c)) { cand[i] = c; cand[ixj] = a; }
                }
            }
            __syncthreads();
        }
    }

    // ---------- probs for top-K prefix, shuffle prefix-sum ----------
    float pv = 0.0f;
    if (tid < K) {
        unsigned k = (unsigned)(cand[tid] >> 32);
        pv = expf(funkey(k) * invT - M) / Z;
    }
    float inc = pv;
    #pragma unroll
    for (int d = 1; d < 64; d <<= 1) { float o = __shfl_up(inc, d); if (lane >= d) inc += o; }
    if (lane == 63) fws[w] = inc;
    __syncthreads();
    if (w == 0) {
        float v = (lane < 16) ? fws[lane] : 0.0f;
        float vi = v;
        #pragma unroll
        for (int d = 1; d < 16; d <<= 1) { float o = __shfl_up(vi, d); if (lane >= d) vi += o; }
        if (lane < 16) fws[16 + lane] = vi - v;
    }
    __syncthreads();
    float cum = inc + fws[16 + w];
    sh_p[tid] = pv;
    sh_c[tid] = cum;
    if (tid == 0) sh_np = K;
    __syncthreads();

    // top-p (exclusive cumsum computed BEFORE masking, as reference)
    if (tid < K) {
        float excl = cum - pv;
        if (excl > top_p) atomicMin(&sh_np, tid);
    }
    __syncthreads();
    int n1 = sh_np;
    float thr = sh_p[0] * min_p;
    if (tid == 0) sh_nf = n1;
    __syncthreads();
    if (tid < n1 && sh_p[tid] < thr) atomicMin(&sh_nf, tid);
    __syncthreads();
    int nf = sh_nf;                        // >= 1
    float total = sh_c[nf - 1];

    // ---------- inverse-CDF sample ----------
    int pred = (tid < nf) && ((sh_c[tid] / total) < uval);
    int rank = __syncthreads_count(pred);
    if (rank > nf - 1) rank = nf - 1;
    if (rank < 0) rank = 0;
    if (tid == 0) {
        unsigned idx = ~(unsigned)(cand[rank] & 0xFFFFFFFFull);
        out_tok[b] = (float)idx;           // ids < 2^24: exact in f32
    }

    // ---------- scatter survivors (out_probs pre-zeroed by K1) ----------
    if (tid < nf) {
        unsigned idx = ~(unsigned)(cand[tid] & 0xFFFFFFFFull);
        out_probs[(size_t)b * V + idx] = sh_p[tid] / total;
    }
}

extern "C" void kernel_launch(void* const* d_in, const int* in_sizes, int n_in,
                              void* d_out, int out_size, void* d_ws, size_t ws_size,
                              hipStream_t stream) {
    const float* logits = (const float*)d_in[0];
    const float* temps  = (const float*)d_in[1];
    const int*   top_ks = (const int*)d_in[2];
    const float* top_ps = (const float*)d_in[3];
    const float* min_ps = (const float*)d_in[4];
    const float* u      = (const float*)d_in[5];
    const int B = in_sizes[1];
    const int V = in_sizes[0] / B;
    float* out_tok   = (float*)d_out;
    float* out_probs = out_tok + B;

    int Vq = (((V + SPLIT - 1) / SPLIT) + 3) & ~3;   // quarter-row, float4-aligned

    char* ws = (char*)d_ws;
    size_t off = 0;
    auto take = [&](size_t bytes) { char* p = ws + off; off = (off + bytes + 255) & ~(size_t)255; return p; };
    float*              ws_ms   = (float*)take((size_t)B * SPLIT * 2 * sizeof(float));
    unsigned*           ws_cnt  = (unsigned*)take((size_t)B * SPLIT * sizeof(unsigned));
    unsigned long long* ws_cand = (unsigned long long*)take((size_t)B * SPLIT * LCAND * sizeof(unsigned long long));
    (void)ws_size;

    k1_scan<<<dim3(SPLIT * B), dim3(TPB), 0, stream>>>(
        logits, temps, top_ks, out_probs, ws_ms, ws_cnt, ws_cand, V, Vq);
    k2_sample<<<dim3(B), dim3(TPB), 0, stream>>>(
        temps, top_ks, top_ps, min_ps, u, ws_ms, ws_cnt, ws_cand,
        out_tok, out_probs, V);
}

// Round 5
// 166.075 us; speedup vs baseline: 1.3183x; 1.0410x over previous
//
#include <hip/hip_runtime.h>
#include <stdint.h>
#include <math.h>

#define TPB 1024
#define NB 2048           // histogram bins (11-bit digits)
#define SPLIT 4           // row split for K1
#define LCAND 2560        // per-quarter-row candidate cap
#define CAND2 2048        // compacted candidate cap in K2
#define PS 4096           // presample count per block
#define L2E 1.44269504088896f

typedef float vfloat4 __attribute__((ext_vector_type(4)));
typedef unsigned long long ull;

// monotonic float -> uint key (ascending key == ascending float)
__device__ __forceinline__ unsigned fkey(float f) {
    unsigned u = __float_as_uint(f);
    return (u & 0x80000000u) ? ~u : (u | 0x80000000u);
}
__device__ __forceinline__ float funkey(unsigned k) {
    unsigned u = (k & 0x80000000u) ? (k ^ 0x80000000u) : ~k;
    return __uint_as_float(u);
}
__device__ __forceinline__ ull packkv(unsigned k, unsigned idx) {
    return ((ull)k << 32) | (ull)(~idx);    // ~idx: desc key sort => asc idx ties
}

// in-place suffix sum of h[0..NB). Caller must barrier before; ends barriered.
__device__ __forceinline__ void suffix_scan_2048(unsigned* h, unsigned* wscr, int tid)
{
    const int lane = tid & 63, w = tid >> 6;
    const int i0 = 2047 - 2 * tid;
    const int i1 = 2046 - 2 * tid;
    unsigned a = h[i0], b = h[i1];
    unsigned s = a + b;
    unsigned inc = s;
    #pragma unroll
    for (int d = 1; d < 64; d <<= 1) { unsigned o = __shfl_up(inc, d); if (lane >= d) inc += o; }
    if (lane == 63) wscr[w] = inc;
    __syncthreads();
    if (w == 0) {
        unsigned v = (lane < 16) ? wscr[lane] : 0u;
        unsigned vi = v;
        #pragma unroll
        for (int d = 1; d < 16; d <<= 1) { unsigned o = __shfl_up(vi, d); if (lane >= d) vi += o; }
        if (lane < 16) wscr[16 + lane] = vi - v;
    }
    __syncthreads();
    unsigned off = wscr[16 + w] + (inc - s);
    h[i0] = off + a;
    h[i1] = off + a + b;
    __syncthreads();
}

// ============================ K1 ============================
// grid = SPLIT*B. Presample-quantile cut, then ONE HBM pass:
// zero out_probs + max-free Z + candidate gather. No full histogram.
__global__ __launch_bounds__(TPB)
void k1_scan(const float* __restrict__ logits,
             const float* __restrict__ temps,
             const int* __restrict__ top_ks,
             float* __restrict__ out_probs,
             float* __restrict__ ws_ms,     // [slot][4] = {Cy, z, Mby, pad}
             unsigned* __restrict__ ws_cut, // [slot]
             unsigned* __restrict__ ws_cnt, // [slot] (raw, may exceed LCAND)
             ull* __restrict__ ws_cand,     // [slot][LCAND]
             int V, int Vq)
{
    const int blk = blockIdx.x;
    const int b = blk / SPLIT, s = blk % SPLIT;
    const int tid = threadIdx.x, lane = tid & 63, w = tid >> 6;
    const int start = s * Vq;
    const int len = min(Vq, V - start);
    const int slot = blk;
    const float invT = 1.0f / temps[b];
    int K = top_ks[b]; K = max(K, 1); K = min(K, 1024);

    __shared__ unsigned hist[NB];
    __shared__ unsigned uscr[32];
    __shared__ float fred[32];
    __shared__ unsigned cnt;
    __shared__ int bstar;

    if (len <= 0) {
        if (tid == 0) {
            ws_ms[4*slot] = -1e30f; ws_ms[4*slot+1] = 0.0f; ws_ms[4*slot+2] = -1e30f;
            ws_cut[slot] = 0u; ws_cnt[slot] = 0u;   // cut=0: vacuous completeness
        }
        return;
    }

    for (int i = tid; i < NB; i += TPB) hist[i] = 0;
    if (tid == 0) { cnt = 0; bstar = 0; }
    __syncthreads();

    const float* __restrict__ row = logits + (size_t)b * V + start;
    const vfloat4* __restrict__ row4 = (const vfloat4*)row;
    float* __restrict__ orow = out_probs + (size_t)b * V + start;
    vfloat4* __restrict__ orow4 = (vfloat4*)orow;
    const int L4 = len >> 2;

    // ---- presample: first nps contiguous elems -> max + tiny histogram ----
    const int nps = min(len, PS);
    float m0 = -1e30f;
    for (int i = tid; i < nps; i += TPB) {
        float lv = row[i];
        m0 = fmaxf(m0, lv);
        atomicAdd(&hist[fkey(lv) >> 21], 1u);
    }
    #pragma unroll
    for (int d = 32; d > 0; d >>= 1) m0 = fmaxf(m0, __shfl_down(m0, d));
    if (lane == 0) fred[w] = m0;
    __syncthreads();
    if (tid == 0) {
        float mm = fred[0];
        for (int j = 1; j < 16; ++j) mm = fmaxf(mm, fred[j]);
        fred[16] = mm;
    }
    __syncthreads();
    const float m0max = fred[16];

    suffix_scan_2048(hist, uscr, tid);
    // target order-stat: ~1.7x the scaled per-block share needed for top-K
    unsigned TGT = (unsigned)((K * 13) / 64 + 16);
    if (TGT > (unsigned)nps) TGT = (unsigned)nps;
    for (int e = tid; e < NB; e += TPB) {
        unsigned Se = hist[e];
        unsigned Sn = (e < NB - 1) ? hist[e + 1] : 0u;
        if (Se >= TGT && Sn < TGT) bstar = e;    // unique writer
    }
    __syncthreads();
    const unsigned cutkey = (unsigned)bstar << 21;
    const float cutval = funkey(cutkey);

    // max-free Z: z = sum 2^((lv*invT - Cy)*L2E), Cy = m0max*invT (offset cancels)
    const float ca = invT * L2E;
    const float cb = -m0max * invT * L2E;

    float z = 0.0f, mb = -1e30f;
    ull* gc = ws_cand + (size_t)slot * LCAND;
    const vfloat4 z4 = (vfloat4)0.0f;

    // ---- single HBM pass: zero + Z + Mb + gather ----
    for (int i = tid; i < L4; i += TPB) {
        vfloat4 v = row4[i];
        __builtin_nontemporal_store(z4, &orow4[i]);
        float x0 = v[0], x1 = v[1], x2 = v[2], x3 = v[3];
        z += exp2f(fmaf(x0, ca, cb)) + exp2f(fmaf(x1, ca, cb))
           + exp2f(fmaf(x2, ca, cb)) + exp2f(fmaf(x3, ca, cb));
        mb = fmaxf(mb, fmaxf(fmaxf(x0, x1), fmaxf(x2, x3)));
        bool c0 = x0 >= cutval, c1 = x1 >= cutval, c2 = x2 >= cutval, c3 = x3 >= cutval;
        if (c0 | c1 | c2 | c3) {
            int n = (int)c0 + (int)c1 + (int)c2 + (int)c3;
            unsigned base = atomicAdd(&cnt, (unsigned)n);
            unsigned bi = (unsigned)(start + (i << 2));
            if (c0) { if (base < LCAND) gc[base] = packkv(fkey(x0), bi + 0); base++; }
            if (c1) { if (base < LCAND) gc[base] = packkv(fkey(x1), bi + 1); base++; }
            if (c2) { if (base < LCAND) gc[base] = packkv(fkey(x2), bi + 2); base++; }
            if (c3) { if (base < LCAND) gc[base] = packkv(fkey(x3), bi + 3); base++; }
        }
    }
    for (int i = (L4 << 2) + tid; i < len; i += TPB) {
        float lv = row[i];
        __builtin_nontemporal_store(0.0f, &orow[i]);
        z += exp2f(fmaf(lv, ca, cb));
        mb = fmaxf(mb, lv);
        if (lv >= cutval) {
            unsigned base = atomicAdd(&cnt, 1u);
            if (base < LCAND) gc[base] = packkv(fkey(lv), (unsigned)(start + i));
        }
    }
    __syncthreads();   // protect fred reuse
    #pragma unroll
    for (int d = 32; d > 0; d >>= 1) {
        z += __shfl_down(z, d);
        mb = fmaxf(mb, __shfl_down(mb, d));
    }
    if (lane == 0) { fred[w] = z; fred[16 + w] = mb; }
    __syncthreads();
    if (tid == 0) {
        float zz = 0.0f, mm = -1e30f;
        for (int j = 0; j < 16; ++j) { zz += fred[j]; mm = fmaxf(mm, fred[16 + j]); }
        ws_ms[4*slot + 0] = m0max * invT;   // Cy (y-space offset)
        ws_ms[4*slot + 1] = zz;             // sum e^(y-Cy)
        ws_ms[4*slot + 2] = mm * invT;      // true block max (y-space)
        ws_cut[slot] = cutkey;
        ws_cnt[slot] = cnt;                 // raw count (overflow detectable)
    }
}

// ============================ K2 ============================
// grid = B. Refine exact threshold from lists, verify exactness (fallback:
// full-row recompute), rank-scatter sort, prefix masks, sample, scatter.
__global__ __launch_bounds__(TPB)
void k2_sample(const float* __restrict__ logits,
               const float* __restrict__ temps,
               const int* __restrict__ top_ks,
               const float* __restrict__ top_ps,
               const float* __restrict__ min_ps,
               const float* __restrict__ uvec,
               const float* __restrict__ ws_ms,
               const unsigned* __restrict__ ws_cut,
               const unsigned* __restrict__ ws_cnt,
               const ull* __restrict__ ws_cand,
               float* __restrict__ out_tok,
               float* __restrict__ out_probs,
               int V)
{
    const int b = blockIdx.x;
    const int tid = threadIdx.x, lane = tid & 63, w = tid >> 6;
    const float invT = 1.0f / temps[b];
    int Korig = top_ks[b]; Korig = max(Korig, 1); Korig = min(Korig, 1024);
    const unsigned Ku = (unsigned)Korig;
    const float top_p = top_ps[b], min_p = min_ps[b], uval = uvec[b];

    // LDS carve (53.5 KB total)
    __shared__ __align__(16) char smem[53504];
    ull*            cand  = (ull*)(smem);                       // [2048] 16 KB
    ull*            cand2 = (ull*)(smem + 16384);               // [2048] 16 KB
    unsigned*       hist  = (unsigned*)(smem + 32768);          // [2049] (8.25 KB region)
    unsigned short* cnts  = (unsigned short*)(smem + 41216);    // [2048] 4 KB
    float*          sh_p  = (float*)(smem + 45312);             // [1024] 4 KB
    float*          sh_c  = (float*)(smem + 49408);             // [1024] 4 KB
    __shared__ unsigned uscr[32];
    __shared__ float fws[32];
    __shared__ unsigned scnt;
    __shared__ int sh_i1, sh_i2;
    __shared__ unsigned sh_u1;

    // ---- combine per-block meta ----
    float Cy[SPLIT], zq[SPLIT], Mbyq[SPLIT];
    unsigned cutq[SPLIT], cntq[SPLIT];
    #pragma unroll
    for (int q = 0; q < SPLIT; ++q) {
        int sl = b * SPLIT + q;
        Cy[q] = ws_ms[4*sl]; zq[q] = ws_ms[4*sl+1]; Mbyq[q] = ws_ms[4*sl+2];
        cutq[q] = ws_cut[sl]; cntq[q] = ws_cnt[sl];
    }
    float Y = -1e30f;
    #pragma unroll
    for (int q = 0; q < SPLIT; ++q) Y = fmaxf(Y, Cy[q]);
    float Z = 0.0f;
    #pragma unroll
    for (int q = 0; q < SPLIT; ++q)
        if (zq[q] > 0.0f) Z += zq[q] * exp2f((Cy[q] - Y) * L2E);

    bool fb = false;
    #pragma unroll
    for (int q = 0; q < SPLIT; ++q) {
        if (cntq[q] > (unsigned)LCAND) fb = true;          // list truncated
        if (Mbyq[q] - Cy[q] > 60.0f) fb = true;            // Z overflow risk
    }
    unsigned cutmax = 0;
    #pragma unroll
    for (int q = 0; q < SPLIT; ++q) cutmax = max(cutmax, cutq[q]);

    unsigned Tkey = 0;
    int count = 0;

    // ---------- fast path: 2-level refine over candidate lists ----------
    if (!fb) {
        for (int i = tid; i < NB; i += TPB) hist[i] = 0;
        if (tid == 0) { sh_i1 = -1; sh_i2 = -1; }
        __syncthreads();
        #pragma unroll
        for (int q = 0; q < SPLIT; ++q) {
            const ull* gc = ws_cand + (size_t)(b * SPLIT + q) * LCAND;
            int nl = min((int)cntq[q], LCAND);
            for (int i = tid; i < nl; i += TPB)
                atomicAdd(&hist[(unsigned)(gc[i] >> 32) >> 21], 1u);
        }
        __syncthreads();
        suffix_scan_2048(hist, uscr, tid);
        for (int e = tid; e < NB; e += TPB) {
            unsigned Se = hist[e], Sn = (e < NB-1) ? hist[e+1] : 0u;
            if (Se >= Ku && Sn < Ku) { sh_i1 = e; sh_u1 = Sn; }
        }
        __syncthreads();
        int b1 = sh_i1;
        unsigned cab = sh_u1;
        if (b1 < 0) fb = true;
        else {
            for (int i = tid; i < NB; i += TPB) hist[i] = 0;
            __syncthreads();
            #pragma unroll
            for (int q = 0; q < SPLIT; ++q) {
                const ull* gc = ws_cand + (size_t)(b * SPLIT + q) * LCAND;
                int nl = min((int)cntq[q], LCAND);
                for (int i = tid; i < nl; i += TPB) {
                    unsigned k = (unsigned)(gc[i] >> 32);
                    if ((int)(k >> 21) == b1) atomicAdd(&hist[(k >> 10) & (NB - 1)], 1u);
                }
            }
            __syncthreads();
            suffix_scan_2048(hist, uscr, tid);
            for (int e = tid; e < NB; e += TPB) {
                unsigned Se = cab + hist[e];
                unsigned Sn = cab + ((e < NB-1) ? hist[e+1] : 0u);
                if (Se >= Ku && Sn < Ku) sh_i2 = e;
            }
            __syncthreads();
            if (sh_i2 < 0) fb = true;
            else {
                Tkey = ((unsigned)b1 << 21) | ((unsigned)sh_i2 << 10);
                if (Tkey < cutmax) fb = true;   // exactness check: τ ≥ all cuts
            }
        }
    }
    if (!fb) {
        if (tid == 0) scnt = 0;
        __syncthreads();
        #pragma unroll
        for (int q = 0; q < SPLIT; ++q) {
            const ull* gc = ws_cand + (size_t)(b * SPLIT + q) * LCAND;
            int nl = min((int)cntq[q], LCAND);
            for (int i = tid; i < nl; i += TPB) {
                ull e = gc[i];
                if ((unsigned)(e >> 32) >= Tkey) {
                    unsigned pos = atomicAdd(&scnt, 1u);
                    if (pos < CAND2) cand[pos] = e;
                }
            }
        }
        __syncthreads();
        if (scnt > (unsigned)CAND2 || scnt < Ku) fb = true;
        else count = (int)scnt;
    }

    // ---------- slow path: full-row exact recompute (correctness net) ----------
    if (fb) {
        const float* __restrict__ row = logits + (size_t)b * V;
        float m = -1e30f, z = 0.0f;
        for (int i = tid; i < V; i += TPB) {
            float y = row[i] * invT;
            float nm = fmaxf(m, y);
            z = z * exp2f((m - nm) * L2E) + exp2f((y - nm) * L2E);
            m = nm;
        }
        sh_p[tid] = m; sh_c[tid] = z;
        __syncthreads();
        for (int d = TPB >> 1; d > 0; d >>= 1) {
            if (tid < d) {
                float m1 = sh_p[tid], z1 = sh_c[tid];
                float m2 = sh_p[tid + d], z2 = sh_c[tid + d];
                float mm = fmaxf(m1, m2);
                sh_c[tid] = z1 * exp2f((m1 - mm) * L2E) + z2 * exp2f((m2 - mm) * L2E);
                sh_p[tid] = mm;
            }
            __syncthreads();
        }
        Y = sh_p[0]; Z = sh_c[0];
        __syncthreads();
        for (int i = tid; i < NB; i += TPB) hist[i] = 0;
        __syncthreads();
        for (int i = tid; i < V; i += TPB) atomicAdd(&hist[fkey(row[i]) >> 21], 1u);
        __syncthreads();
        suffix_scan_2048(hist, uscr, tid);
        for (int e = tid; e < NB; e += TPB) {
            unsigned Se = hist[e], Sn = (e < NB-1) ? hist[e+1] : 0u;
            if (Se >= Ku && Sn < Ku) { sh_i1 = e; sh_u1 = Sn; }
        }
        __syncthreads();
        int b1 = sh_i1;
        unsigned cab = sh_u1;
        for (int i = tid; i < NB; i += TPB) hist[i] = 0;
        __syncthreads();
        for (int i = tid; i < V; i += TPB) {
            unsigned k = fkey(row[i]);
            if ((int)(k >> 21) == b1) atomicAdd(&hist[(k >> 10) & (NB - 1)], 1u);
        }
        __syncthreads();
        suffix_scan_2048(hist, uscr, tid);
        for (int e = tid; e < NB; e += TPB) {
            unsigned Se = cab + hist[e];
            unsigned Sn = cab + ((e < NB-1) ? hist[e+1] : 0u);
            if (Se >= Ku && Sn < Ku) sh_i2 = e;
        }
        __syncthreads();
        Tkey = ((unsigned)b1 << 21) | ((unsigned)sh_i2 << 10);
        if (tid == 0) scnt = 0;
        __syncthreads();
        for (int i = tid; i < V; i += TPB) {
            unsigned k = fkey(row[i]);
            if (k >= Tkey) {
                unsigned pos = atomicAdd(&scnt, 1u);
                if (pos < CAND2) cand[pos] = packkv(k, (unsigned)i);
            }
        }
        __syncthreads();
        count = (scnt < (unsigned)CAND2) ? (int)scnt : CAND2;
    }

    int K = min(Korig, count);

    // ---------- sort: rank-scatter (bitonic fallback for fat bins) ----------
    unsigned mk = 0;
    for (int i = tid; i < count; i += TPB) mk = max(mk, (unsigned)(cand[i] >> 32));
    #pragma unroll
    for (int d = 32; d > 0; d >>= 1) mk = max(mk, __shfl_down(mk, d));
    if (lane == 0) uscr[w] = mk;
    __syncthreads();
    if (tid == 0) {
        unsigned m2 = 0;
        for (int j = 0; j < 16; ++j) m2 = max(m2, uscr[j]);
        uscr[16] = m2;
    }
    __syncthreads();
    const unsigned maxkey = uscr[16];
    const unsigned range = maxkey - Tkey;
    int shift = 0;
    while ((range >> shift) > (NB - 1)) shift++;

    for (int i = tid; i <= NB; i += TPB) hist[i] = 0;   // incl hist[2048]
    __syncthreads();
    for (int i = tid; i < count; i += TPB)
        atomicAdd(&hist[((unsigned)(cand[i] >> 32) - Tkey) >> shift], 1u);
    __syncthreads();
    unsigned mc = 0;
    for (int i = tid; i < NB; i += TPB) {
        unsigned h = hist[i];
        cnts[i] = (unsigned short)h;
        mc = max(mc, h);
    }
    #pragma unroll
    for (int d = 32; d > 0; d >>= 1) mc = max(mc, __shfl_down(mc, d));
    if (lane == 0) uscr[w] = mc;
    __syncthreads();
    if (tid == 0) {
        unsigned m2 = 0;
        for (int j = 0; j < 16; ++j) m2 = max(m2, uscr[j]);
        uscr[17] = m2;
    }
    __syncthreads();
    const bool use_bitonic = (uscr[17] > 48u);
    ull* srt;
    if (!use_bitonic) {
        suffix_scan_2048(hist, uscr, tid);   // hist[2048] stays 0
        for (int i = tid; i < count; i += TPB) {
            ull v = cand[i];
            unsigned bin = ((unsigned)(v >> 32) - Tkey) >> shift;
            unsigned pos = atomicAdd(&hist[bin + 1], 1u);  // base = S[bin+1]
            cand2[pos] = v;
        }
        __syncthreads();
        for (int bn = tid; bn < NB; bn += TPB) {           // fix multi-elem bins
            int c = (int)cnts[bn];
            if (c >= 2) {
                int st = (int)hist[bn + 1] - c;
                for (int x = 1; x < c; ++x) {
                    ull key = cand2[st + x];
                    int y = x - 1;
                    while (y >= 0 && cand2[st + y] < key) { cand2[st + y + 1] = cand2[st + y]; --y; }
                    cand2[st + y + 1] = key;
                }
            }
        }
        __syncthreads();
        srt = cand2;
    } else {
        int n_sort = 1;
        while (n_sort < count) n_sort <<= 1;
        for (int i = tid; i < n_sort; i += TPB)
            if (i >= count) cand[i] = 0ull;
        __syncthreads();
        for (int kk = 2; kk <= n_sort; kk <<= 1) {
            for (int j = kk >> 1; j > 0; j >>= 1) {
                for (int i = tid; i < n_sort; i += TPB) {
                    int ixj = i ^ j;
                    if (ixj > i) {
                        ull a = cand[i], c = cand[ixj];
                        bool up = (i & kk) == 0;
                        if (up ? (a < c) : (a > c)) { cand[i] = c; cand[ixj] = a; }
                    }
                }
                __syncthreads();
            }
        }
        srt = cand;
    }

    // ---------- probs for top-K prefix, shuffle prefix-sum ----------
    float pv = 0.0f;
    if (tid < K) {
        unsigned k = (unsigned)(srt[tid] >> 32);
        pv = exp2f((funkey(k) * invT - Y) * L2E) / Z;
    }
    float inc = pv;
    #pragma unroll
    for (int d = 1; d < 64; d <<= 1) { float o = __shfl_up(inc, d); if (lane >= d) inc += o; }
    if (lane == 63) fws[w] = inc;
    __syncthreads();
    if (w == 0) {
        float v = (lane < 16) ? fws[lane] : 0.0f;
        float vi = v;
        #pragma unroll
        for (int d = 1; d < 16; d <<= 1) { float o = __shfl_up(vi, d); if (lane >= d) vi += o; }
        if (lane < 16) fws[16 + lane] = vi - v;
    }
    __syncthreads();
    float cum = inc + fws[16 + w];
    sh_p[tid] = pv;
    sh_c[tid] = cum;
    if (tid == 0) sh_i1 = K;
    __syncthreads();

    // top-p (exclusive cumsum BEFORE masking, as reference)
    if (tid < K) {
        float excl = cum - pv;
        if (excl > top_p) atomicMin(&sh_i1, tid);
    }
    __syncthreads();
    int n1 = sh_i1;
    float thr = sh_p[0] * min_p;
    if (tid == 0) sh_i2 = n1;
    __syncthreads();
    if (tid < n1 && sh_p[tid] < thr) atomicMin(&sh_i2, tid);
    __syncthreads();
    int nf = sh_i2;                         // >= 1
    float total = sh_c[nf - 1];

    // ---------- inverse-CDF sample ----------
    int pred = (tid < nf) && ((sh_c[tid] / total) < uval);
    int rank = __syncthreads_count(pred);
    if (rank > nf - 1) rank = nf - 1;
    if (rank < 0) rank = 0;
    if (tid == 0)
        out_tok[b] = (float)(~(unsigned)(srt[rank] & 0xFFFFFFFFull));

    // ---------- scatter survivors (out_probs pre-zeroed by K1) ----------
    if (tid < nf) {
        unsigned idx = ~(unsigned)(srt[tid] & 0xFFFFFFFFull);
        out_probs[(size_t)b * V + idx] = sh_p[tid] / total;
    }
}

extern "C" void kernel_launch(void* const* d_in, const int* in_sizes, int n_in,
                              void* d_out, int out_size, void* d_ws, size_t ws_size,
                              hipStream_t stream) {
    const float* logits = (const float*)d_in[0];
    const float* temps  = (const float*)d_in[1];
    const int*   top_ks = (const int*)d_in[2];
    const float* top_ps = (const float*)d_in[3];
    const float* min_ps = (const float*)d_in[4];
    const float* u      = (const float*)d_in[5];
    const int B = in_sizes[1];
    const int V = in_sizes[0] / B;
    float* out_tok   = (float*)d_out;
    float* out_probs = out_tok + B;

    int Vq = (((V + SPLIT - 1) / SPLIT) + 3) & ~3;   // quarter-row, float4-aligned

    char* ws = (char*)d_ws;
    size_t off = 0;
    auto take = [&](size_t bytes) { char* p = ws + off; off = (off + bytes + 255) & ~(size_t)255; return p; };
    float*    ws_ms   = (float*)take((size_t)B * SPLIT * 4 * sizeof(float));
    unsigned* ws_cut  = (unsigned*)take((size_t)B * SPLIT * sizeof(unsigned));
    unsigned* ws_cnt  = (unsigned*)take((size_t)B * SPLIT * sizeof(unsigned));
    ull*      ws_cand = (ull*)take((size_t)B * SPLIT * LCAND * sizeof(ull));
    (void)ws_size;

    k1_scan<<<dim3(SPLIT * B), dim3(TPB), 0, stream>>>(
        logits, temps, top_ks, out_probs, ws_ms, ws_cut, ws_cnt, ws_cand, V, Vq);
    k2_sample<<<dim3(B), dim3(TPB), 0, stream>>>(
        logits, temps, top_ks, top_ps, min_ps, u, ws_ms, ws_cut, ws_cnt, ws_cand,
        out_tok, out_probs, V);
}

// Round 6
// 155.498 us; speedup vs baseline: 1.4080x; 1.0680x over previous
//
#include <hip/hip_runtime.h>
#include <stdint.h>
#include <math.h>

#define TPB 1024
#define NB 2048           // histogram bins
#define SPLIT 4           // row split for scan blocks
#define LCAND 2560        // per-quarter-row candidate cap
#define CAND2 2048        // candidate cap in K2
#define PS 4096           // presample count per block
#define L2E 1.44269504088896f

typedef float vfloat4 __attribute__((ext_vector_type(4)));
typedef unsigned long long ull;

// monotonic float -> uint key (ascending key == ascending float)
__device__ __forceinline__ unsigned fkey(float f) {
    unsigned u = __float_as_uint(f);
    return (u & 0x80000000u) ? ~u : (u | 0x80000000u);
}
__device__ __forceinline__ float funkey(unsigned k) {
    unsigned u = (k & 0x80000000u) ? (k ^ 0x80000000u) : ~k;
    return __uint_as_float(u);
}
__device__ __forceinline__ ull packkv(unsigned k, unsigned idx) {
    return ((ull)k << 32) | (ull)(~idx);    // ~idx: desc key sort => asc idx ties
}

// in-place suffix sum of h[0..NB). Caller must barrier before; ends barriered.
__device__ __forceinline__ void suffix_scan_2048(unsigned* h, unsigned* wscr, int tid)
{
    const int lane = tid & 63, w = tid >> 6;
    const int i0 = 2047 - 2 * tid;
    const int i1 = 2046 - 2 * tid;
    unsigned a = h[i0], b = h[i1];
    unsigned s = a + b;
    unsigned inc = s;
    #pragma unroll
    for (int d = 1; d < 64; d <<= 1) { unsigned o = __shfl_up(inc, d); if (lane >= d) inc += o; }
    if (lane == 63) wscr[w] = inc;
    __syncthreads();
    if (w == 0) {
        unsigned v = (lane < 16) ? wscr[lane] : 0u;
        unsigned vi = v;
        #pragma unroll
        for (int d = 1; d < 16; d <<= 1) { unsigned o = __shfl_up(vi, d); if (lane >= d) vi += o; }
        if (lane < 16) wscr[16 + lane] = vi - v;
    }
    __syncthreads();
    unsigned off = wscr[16 + w] + (inc - s);
    h[i0] = off + a;
    h[i1] = off + a + b;
    __syncthreads();
}

// ============================ K1 ============================
// grid = 3*SPLIT*B. role = blk%3: role 0 -> scan (read-only), roles 1,2 ->
// zero out_probs (overlaps writes with scan reads across co-resident blocks).
__global__ __launch_bounds__(TPB)
void k1_scan(const float* __restrict__ logits,
             const float* __restrict__ temps,
             const int* __restrict__ top_ks,
             float* __restrict__ out_probs,
             float* __restrict__ ws_meta,   // [slot][4] {Cy, z, Mby, maxkey bits}
             unsigned* __restrict__ ws_cut, // [slot]
             unsigned* __restrict__ ws_cnt, // [slot] raw count (overflow visible)
             ull* __restrict__ ws_cand,     // [slot][LCAND]
             int V, int Vq, int n)          // n = B*V
{
    const int blk = blockIdx.x;
    const int tid = threadIdx.x, lane = tid & 63, w = tid >> 6;
    const int role = blk % 3;

    if (role != 0) {
        // ---------- zero role ----------
        const int ZB = (gridDim.x / 3) * 2;
        const int zid = (blk / 3) * 2 + (role - 1);
        const int n4 = n >> 2;
        vfloat4* p4 = (vfloat4*)out_probs;
        const vfloat4 z4 = (vfloat4)0.0f;
        const int step = ZB * TPB;
        for (int i = zid * TPB + tid; i < n4; i += step) p4[i] = z4;
        for (int i = (n4 << 2) + zid * TPB + tid; i < n; i += step) out_probs[i] = 0.0f;
        return;
    }

    // ---------- scan role ----------
    const int sblk = blk / 3;
    const int b = sblk / SPLIT, s = sblk % SPLIT;
    const int start = s * Vq;
    const int len = min(Vq, V - start);
    const int slot = sblk;
    const float invT = 1.0f / temps[b];
    int K = top_ks[b]; K = max(K, 1); K = min(K, 1024);

    __shared__ unsigned hist[NB];
    __shared__ unsigned uscr[32];
    __shared__ float fred[32];
    __shared__ unsigned cnt;
    __shared__ int bstar;

    if (len <= 0) {
        if (tid == 0) {
            ws_meta[4*slot] = -1e30f; ws_meta[4*slot+1] = 0.0f;
            ws_meta[4*slot+2] = -1e30f; ws_meta[4*slot+3] = __uint_as_float(0u);
            ws_cut[slot] = 0u; ws_cnt[slot] = 0u;
        }
        return;
    }

    for (int i = tid; i < NB; i += TPB) hist[i] = 0;
    if (tid == 0) { cnt = 0; bstar = 0; }
    __syncthreads();

    const float* __restrict__ row = logits + (size_t)b * V + start;
    const vfloat4* __restrict__ row4 = (const vfloat4*)row;
    const int L4 = len >> 2;

    // ---- presample: first nps elems -> max + histogram ----
    const int nps = min(len, PS);
    float m0 = -1e30f;
    for (int i = tid; i < nps; i += TPB) {
        float lv = row[i];
        m0 = fmaxf(m0, lv);
        atomicAdd(&hist[fkey(lv) >> 21], 1u);
    }
    #pragma unroll
    for (int d = 32; d > 0; d >>= 1) m0 = fmaxf(m0, __shfl_down(m0, d));
    if (lane == 0) fred[w] = m0;
    __syncthreads();
    if (tid == 0) {
        float mm = fred[0];
        for (int j = 1; j < 16; ++j) mm = fmaxf(mm, fred[j]);
        fred[16] = mm;
    }
    __syncthreads();
    const float m0max = fred[16];

    suffix_scan_2048(hist, uscr, tid);
    // statistical target: s = expected global-top-K hits in presample
    float sexp = (float)K * (float)nps / (float)V;
    unsigned TGT = (unsigned)(sexp + 6.0f * sqrtf(sexp) + 16.5f);
    if (TGT > (unsigned)nps) TGT = (unsigned)nps;
    for (int e = tid; e < NB; e += TPB) {
        unsigned Se = hist[e];
        unsigned Sn = (e < NB - 1) ? hist[e + 1] : 0u;
        if (Se >= TGT && Sn < TGT) bstar = e;    // unique writer
    }
    __syncthreads();
    const unsigned cutkey = (unsigned)bstar << 21;
    const float cutval = funkey(cutkey);

    // max-free Z around presample max (offset cancels in k2)
    const float ca = invT * L2E;
    const float cb = -m0max * invT * L2E;

    float z = 0.0f, mb = -1e30f;
    ull* gc = ws_cand + (size_t)slot * LCAND;

    // ---- single READ-ONLY pass: Z + block max + candidate gather ----
    for (int i = tid; i < L4; i += TPB) {
        vfloat4 v = row4[i];
        float x0 = v[0], x1 = v[1], x2 = v[2], x3 = v[3];
        z += exp2f(fmaf(x0, ca, cb)) + exp2f(fmaf(x1, ca, cb))
           + exp2f(fmaf(x2, ca, cb)) + exp2f(fmaf(x3, ca, cb));
        mb = fmaxf(mb, fmaxf(fmaxf(x0, x1), fmaxf(x2, x3)));
        bool c0 = x0 >= cutval, c1 = x1 >= cutval, c2 = x2 >= cutval, c3 = x3 >= cutval;
        if (c0 | c1 | c2 | c3) {
            int nh = (int)c0 + (int)c1 + (int)c2 + (int)c3;
            unsigned base = atomicAdd(&cnt, (unsigned)nh);
            unsigned bi = (unsigned)(start + (i << 2));
            if (c0) { if (base < LCAND) gc[base] = packkv(fkey(x0), bi + 0); base++; }
            if (c1) { if (base < LCAND) gc[base] = packkv(fkey(x1), bi + 1); base++; }
            if (c2) { if (base < LCAND) gc[base] = packkv(fkey(x2), bi + 2); base++; }
            if (c3) { if (base < LCAND) gc[base] = packkv(fkey(x3), bi + 3); base++; }
        }
    }
    for (int i = (L4 << 2) + tid; i < len; i += TPB) {
        float lv = row[i];
        z += exp2f(fmaf(lv, ca, cb));
        mb = fmaxf(mb, lv);
        if (lv >= cutval) {
            unsigned base = atomicAdd(&cnt, 1u);
            if (base < LCAND) gc[base] = packkv(fkey(lv), (unsigned)(start + i));
        }
    }
    __syncthreads();   // protect fred reuse
    #pragma unroll
    for (int d = 32; d > 0; d >>= 1) {
        z += __shfl_down(z, d);
        mb = fmaxf(mb, __shfl_down(mb, d));
    }
    if (lane == 0) { fred[w] = z; fred[16 + w] = mb; }
    __syncthreads();
    if (tid == 0) {
        float zz = 0.0f, mm = -1e30f;
        for (int j = 0; j < 16; ++j) { zz += fred[j]; mm = fmaxf(mm, fred[16 + j]); }
        ws_meta[4*slot + 0] = m0max * invT;          // Cy
        ws_meta[4*slot + 1] = zz;                    // sum 2^((x-m0max)*invT*L2E)
        ws_meta[4*slot + 2] = mm * invT;             // true block max (y-space)
        ws_meta[4*slot + 3] = __uint_as_float(fkey(mm));  // block max key
        ws_cut[slot] = cutkey;
        ws_cnt[slot] = cnt;
    }
}

// ============================ K2 ============================
// grid = B. Single-pass adaptive threshold + scatter-sort; full-row fallback.
__global__ __launch_bounds__(TPB)
void k2_sample(const float* __restrict__ logits,
               const float* __restrict__ temps,
               const int* __restrict__ top_ks,
               const float* __restrict__ top_ps,
               const float* __restrict__ min_ps,
               const float* __restrict__ uvec,
               const float* __restrict__ ws_meta,
               const unsigned* __restrict__ ws_cut,
               const unsigned* __restrict__ ws_cnt,
               const ull* __restrict__ ws_cand,
               float* __restrict__ out_tok,
               float* __restrict__ out_probs,
               int V)
{
    const int b = blockIdx.x;
    const int tid = threadIdx.x, lane = tid & 63, w = tid >> 6;
    const float invT = 1.0f / temps[b];
    int Korig = top_ks[b]; Korig = max(Korig, 1); Korig = min(Korig, 1024);
    const unsigned Ku = (unsigned)Korig;
    const float top_p = top_ps[b], min_p = min_ps[b], uval = uvec[b];

    // LDS carve
    __shared__ __align__(16) char smem[53504];
    ull*            cand  = (ull*)(smem);                       // [2048] (fb path)
    ull*            cand2 = (ull*)(smem + 16384);               // [2048] sorted dest
    unsigned*       hist  = (unsigned*)(smem + 32768);          // [2049]
    unsigned short* cnts  = (unsigned short*)(smem + 41216);    // [2048]
    float*          sh_p  = (float*)(smem + 45312);             // [1024]
    float*          sh_c  = (float*)(smem + 49408);             // [1024]
    __shared__ unsigned uscr[32];
    __shared__ float fws[32];
    __shared__ unsigned scnt;
    __shared__ int sh_i1, sh_i2;
    __shared__ unsigned sh_u1;

    // ---- combine per-block meta ----
    float Cy[SPLIT], zq[SPLIT], Mbyq[SPLIT];
    unsigned cutq[SPLIT], cntq[SPLIT], mkq[SPLIT];
    #pragma unroll
    for (int q = 0; q < SPLIT; ++q) {
        int sl = b * SPLIT + q;
        Cy[q] = ws_meta[4*sl]; zq[q] = ws_meta[4*sl+1]; Mbyq[q] = ws_meta[4*sl+2];
        mkq[q] = __float_as_uint(ws_meta[4*sl+3]);
        cutq[q] = ws_cut[sl]; cntq[q] = ws_cnt[sl];
    }
    float Y = -1e30f;
    #pragma unroll
    for (int q = 0; q < SPLIT; ++q) Y = fmaxf(Y, Cy[q]);
    float Z = 0.0f;
    #pragma unroll
    for (int q = 0; q < SPLIT; ++q)
        if (zq[q] > 0.0f) Z += zq[q] * exp2f((Cy[q] - Y) * L2E);

    bool fb = false;
    unsigned cutmax = 0, mincut = 0xFFFFFFFFu, maxkey = 0;
    #pragma unroll
    for (int q = 0; q < SPLIT; ++q) {
        if (cntq[q] > (unsigned)LCAND) fb = true;          // list truncated
        if (cntq[q] > 0u) {
            if (Mbyq[q] - Cy[q] > 60.0f) fb = true;        // Z overflow risk
            cutmax = max(cutmax, cutq[q]);
            mincut = min(mincut, cutq[q]);
            maxkey = max(maxkey, mkq[q]);
        }
    }
    if (mincut == 0xFFFFFFFFu) fb = true;                  // no data at all

    const unsigned base = mincut;
    const unsigned range = maxkey - base;
    int shift = 0;
    while ((range >> shift) > (unsigned)(NB - 1)) shift++;

    unsigned Tkeyb = 0;
    int count = 0, bstar = 0;

    // ---------- fast path: one adaptive histogram over candidate lists ----------
    if (!fb) {
        for (int i = tid; i <= NB; i += TPB) hist[i] = 0;   // incl hist[2048]
        if (tid == 0) { sh_i1 = -1; scnt = 0; }
        __syncthreads();
        #pragma unroll
        for (int q = 0; q < SPLIT; ++q) {
            const ull* gc = ws_cand + (size_t)(b * SPLIT + q) * LCAND;
            int nl = min((int)cntq[q], LCAND);
            for (int i = tid; i < nl; i += TPB)
                atomicAdd(&hist[((unsigned)(gc[i] >> 32) - base) >> shift], 1u);
        }
        __syncthreads();
        unsigned fat = 0;
        for (int i = tid; i < NB; i += TPB) {
            unsigned h = hist[i];
            cnts[i] = (unsigned short)h;
            fat = max(fat, h);
        }
        #pragma unroll
        for (int d = 32; d > 0; d >>= 1) fat = max(fat, __shfl_down(fat, d));
        if (lane == 0) uscr[w] = fat;
        __syncthreads();
        if (tid == 0) {
            unsigned m2 = 0;
            for (int j = 0; j < 16; ++j) m2 = max(m2, uscr[j]);
            uscr[16] = m2;
        }
        __syncthreads();
        if (uscr[16] > 64u) fb = true;                      // fat bin -> fallback
    }
    if (!fb) {
        suffix_scan_2048(hist, uscr, tid);
        for (int e = tid; e < NB; e += TPB) {
            unsigned Se = hist[e], Sn = (e < NB - 1) ? hist[e + 1] : 0u;
            if (Se >= Ku && Sn < Ku) { sh_i1 = e; sh_u1 = Se; }
        }
        __syncthreads();
        if (sh_i1 < 0) fb = true;
        else {
            bstar = sh_i1;
            count = (int)sh_u1;
            Tkeyb = base + ((unsigned)bstar << shift);
            if (Tkeyb < cutmax || count > CAND2) fb = true; // exactness guards
        }
    }
    if (!fb) {
        // scatter directly into sorted-by-bin position
        #pragma unroll
        for (int q = 0; q < SPLIT; ++q) {
            const ull* gc = ws_cand + (size_t)(b * SPLIT + q) * LCAND;
            int nl = min((int)cntq[q], LCAND);
            for (int i = tid; i < nl; i += TPB) {
                ull e = gc[i];
                unsigned k = (unsigned)(e >> 32);
                if (k >= Tkeyb) {
                    unsigned bin = (k - base) >> shift;
                    unsigned pos = atomicAdd(&hist[bin + 1], 1u);  // base S[bin+1]
                    cand2[pos] = e;
                }
            }
        }
        __syncthreads();
        for (int e = bstar + tid; e < NB; e += TPB) {       // fix multi-elem bins
            int c = (int)cnts[e];
            if (c >= 2) {
                int st = (int)hist[e + 1] - c;
                for (int x = 1; x < c; ++x) {
                    ull key = cand2[st + x];
                    int y = x - 1;
                    while (y >= 0 && cand2[st + y] < key) { cand2[st + y + 1] = cand2[st + y]; --y; }
                    cand2[st + y + 1] = key;
                }
            }
        }
        __syncthreads();
    }

    // ---------- slow path: full-row exact recompute (correctness net) ----------
    if (fb) {
        const float* __restrict__ row = logits + (size_t)b * V;
        float m = -1e30f, z = 0.0f;
        for (int i = tid; i < V; i += TPB) {
            float y = row[i] * invT;
            float nm = fmaxf(m, y);
            z = z * exp2f((m - nm) * L2E) + exp2f((y - nm) * L2E);
            m = nm;
        }
        sh_p[tid] = m; sh_c[tid] = z;
        __syncthreads();
        for (int d = TPB >> 1; d > 0; d >>= 1) {
            if (tid < d) {
                float m1 = sh_p[tid], z1 = sh_c[tid];
                float m2 = sh_p[tid + d], z2 = sh_c[tid + d];
                float mm = fmaxf(m1, m2);
                sh_c[tid] = z1 * exp2f((m1 - mm) * L2E) + z2 * exp2f((m2 - mm) * L2E);
                sh_p[tid] = mm;
            }
            __syncthreads();
        }
        Y = sh_p[0]; Z = sh_c[0];
        __syncthreads();
        for (int i = tid; i < NB; i += TPB) hist[i] = 0;
        if (tid == 0) { sh_i1 = 0; sh_i2 = 0; sh_u1 = 0; }
        __syncthreads();
        for (int i = tid; i < V; i += TPB) atomicAdd(&hist[fkey(row[i]) >> 21], 1u);
        __syncthreads();
        suffix_scan_2048(hist, uscr, tid);
        for (int e = tid; e < NB; e += TPB) {
            unsigned Se = hist[e], Sn = (e < NB-1) ? hist[e+1] : 0u;
            if (Se >= Ku && Sn < Ku) { sh_i1 = e; sh_u1 = Sn; }
        }
        __syncthreads();
        int b1 = sh_i1;
        unsigned cab = sh_u1;
        for (int i = tid; i < NB; i += TPB) hist[i] = 0;
        __syncthreads();
        for (int i = tid; i < V; i += TPB) {
            unsigned k = fkey(row[i]);
            if ((int)(k >> 21) == b1) atomicAdd(&hist[(k >> 10) & (NB - 1)], 1u);
        }
        __syncthreads();
        suffix_scan_2048(hist, uscr, tid);
        for (int e = tid; e < NB; e += TPB) {
            unsigned Se = cab + hist[e];
            unsigned Sn = cab + ((e < NB-1) ? hist[e+1] : 0u);
            if (Se >= Ku && Sn < Ku) sh_i2 = e;
        }
        __syncthreads();
        unsigned Tkey = ((unsigned)b1 << 21) | ((unsigned)sh_i2 << 10);
        if (tid == 0) scnt = 0;
        __syncthreads();
        for (int i = tid; i < V; i += TPB) {
            unsigned k = fkey(row[i]);
            if (k >= Tkey) {
                unsigned pos = atomicAdd(&scnt, 1u);
                if (pos < CAND2) cand[pos] = packkv(k, (unsigned)i);
            }
        }
        __syncthreads();
        count = (scnt < (unsigned)CAND2) ? (int)scnt : CAND2;

        int n_sort = 1;
        while (n_sort < count) n_sort <<= 1;
        for (int i = tid; i < n_sort; i += TPB)
            if (i >= count) cand[i] = 0ull;
        __syncthreads();
        for (int kk = 2; kk <= n_sort; kk <<= 1) {
            for (int j = kk >> 1; j > 0; j >>= 1) {
                for (int i = tid; i < n_sort; i += TPB) {
                    int ixj = i ^ j;
                    if (ixj > i) {
                        ull a = cand[i], c = cand[ixj];
                        bool up = (i & kk) == 0;
                        if (up ? (a < c) : (a > c)) { cand[i] = c; cand[ixj] = a; }
                    }
                }
                __syncthreads();
            }
        }
    }

    ull* srt = fb ? cand : cand2;
    int K = min(Korig, count);

    // ---------- probs for top-K prefix, shuffle prefix-sum ----------
    float pv = 0.0f;
    if (tid < K) {
        unsigned k = (unsigned)(srt[tid] >> 32);
        pv = exp2f((funkey(k) * invT - Y) * L2E) / Z;
    }
    float inc = pv;
    #pragma unroll
    for (int d = 1; d < 64; d <<= 1) { float o = __shfl_up(inc, d); if (lane >= d) inc += o; }
    if (lane == 63) fws[w] = inc;
    __syncthreads();
    if (w == 0) {
        float v = (lane < 16) ? fws[lane] : 0.0f;
        float vi = v;
        #pragma unroll
        for (int d = 1; d < 16; d <<= 1) { float o = __shfl_up(vi, d); if (lane >= d) vi += o; }
        if (lane < 16) fws[16 + lane] = vi - v;
    }
    __syncthreads();
    float cum = inc + fws[16 + w];
    sh_p[tid] = pv;
    sh_c[tid] = cum;
    if (tid == 0) sh_i1 = K;
    __syncthreads();

    // top-p (exclusive cumsum BEFORE masking, as reference)
    if (tid < K) {
        float excl = cum - pv;
        if (excl > top_p) atomicMin(&sh_i1, tid);
    }
    __syncthreads();
    int n1 = sh_i1;
    float thr = sh_p[0] * min_p;
    if (tid == 0) sh_i2 = n1;
    __syncthreads();
    if (tid < n1 && sh_p[tid] < thr) atomicMin(&sh_i2, tid);
    __syncthreads();
    int nf = sh_i2;                         // >= 1
    float total = sh_c[nf - 1];

    // ---------- inverse-CDF sample ----------
    int pred = (tid < nf) && ((sh_c[tid] / total) < uval);
    int rank = __syncthreads_count(pred);
    if (rank > nf - 1) rank = nf - 1;
    if (rank < 0) rank = 0;
    if (tid == 0)
        out_tok[b] = (float)(~(unsigned)(srt[rank] & 0xFFFFFFFFull));

    // ---------- scatter survivors (out_probs zeroed by K1) ----------
    if (tid < nf) {
        unsigned idx = ~(unsigned)(srt[tid] & 0xFFFFFFFFull);
        out_probs[(size_t)b * V + idx] = sh_p[tid] / total;
    }
}

extern "C" void kernel_launch(void* const* d_in, const int* in_sizes, int n_in,
                              void* d_out, int out_size, void* d_ws, size_t ws_size,
                              hipStream_t stream) {
    const float* logits = (const float*)d_in[0];
    const float* temps  = (const float*)d_in[1];
    const int*   top_ks = (const int*)d_in[2];
    const float* top_ps = (const float*)d_in[3];
    const float* min_ps = (const float*)d_in[4];
    const float* u      = (const float*)d_in[5];
    const int B = in_sizes[1];
    const int V = in_sizes[0] / B;
    float* out_tok   = (float*)d_out;
    float* out_probs = out_tok + B;

    int Vq = (((V + SPLIT - 1) / SPLIT) + 3) & ~3;   // quarter-row, float4-aligned
    int n = B * V;

    char* ws = (char*)d_ws;
    size_t off = 0;
    auto take = [&](size_t bytes) { char* p = ws + off; off = (off + bytes + 255) & ~(size_t)255; return p; };
    float*    ws_meta = (float*)take((size_t)B * SPLIT * 4 * sizeof(float));
    unsigned* ws_cut  = (unsigned*)take((size_t)B * SPLIT * sizeof(unsigned));
    unsigned* ws_cnt  = (unsigned*)take((size_t)B * SPLIT * sizeof(unsigned));
    ull*      ws_cand = (ull*)take((size_t)B * SPLIT * LCAND * sizeof(ull));
    (void)ws_size;

    k1_scan<<<dim3(3 * SPLIT * B), dim3(TPB), 0, stream>>>(
        logits, temps, top_ks, out_probs, ws_meta, ws_cut, ws_cnt, ws_cand, V, Vq, n);
    k2_sample<<<dim3(B), dim3(TPB), 0, stream>>>(
        logits, temps, top_ks, top_ps, min_ps, u, ws_meta, ws_cut, ws_cnt, ws_cand,
        out_tok, out_probs, V);
}

// Round 7
// 152.525 us; speedup vs baseline: 1.4354x; 1.0195x over previous
//
#include <hip/hip_runtime.h>
#include <stdint.h>
#include <math.h>

#define TPB 1024
#define NB 2048           // histogram bins
#define SPLIT 4           // row split for scan blocks
#define LCAND 2560        // per-quarter-row candidate cap
#define CAND2 2048        // candidate cap in K2
#define PS 4096           // presample count per block
#define L2E 1.44269504088896f

typedef float vfloat4 __attribute__((ext_vector_type(4)));
typedef unsigned long long ull;

// monotonic float -> uint key (ascending key == ascending float)
__device__ __forceinline__ unsigned fkey(float f) {
    unsigned u = __float_as_uint(f);
    return (u & 0x80000000u) ? ~u : (u | 0x80000000u);
}
__device__ __forceinline__ float funkey(unsigned k) {
    unsigned u = (k & 0x80000000u) ? (k ^ 0x80000000u) : ~k;
    return __uint_as_float(u);
}
__device__ __forceinline__ ull packkv(unsigned k, unsigned idx) {
    return ((ull)k << 32) | (ull)(~idx);    // ~idx: desc key sort => asc idx ties
}

// in-place suffix sum of h[0..NB). Caller must barrier before; ends barriered.
__device__ __forceinline__ void suffix_scan_2048(unsigned* h, unsigned* wscr, int tid)
{
    const int lane = tid & 63, w = tid >> 6;
    const int i0 = 2047 - 2 * tid;
    const int i1 = 2046 - 2 * tid;
    unsigned a = h[i0], b = h[i1];
    unsigned s = a + b;
    unsigned inc = s;
    #pragma unroll
    for (int d = 1; d < 64; d <<= 1) { unsigned o = __shfl_up(inc, d); if (lane >= d) inc += o; }
    if (lane == 63) wscr[w] = inc;
    __syncthreads();
    if (w == 0) {
        unsigned v = (lane < 16) ? wscr[lane] : 0u;
        unsigned vi = v;
        #pragma unroll
        for (int d = 1; d < 16; d <<= 1) { unsigned o = __shfl_up(vi, d); if (lane >= d) vi += o; }
        if (lane < 16) wscr[16 + lane] = vi - v;
    }
    __syncthreads();
    unsigned off = wscr[16 + w] + (inc - s);
    h[i0] = off + a;
    h[i1] = off + a + b;
    __syncthreads();
}

// ============================ K1 ============================
// grid = SPLIT*B. Presample cut -> nt-zero epilogue (issued first, drains
// async) -> batched read-only pass: 4 loads in flight, 4 indep Z accums,
// candidate gather. No block-max tracking (k2 derives it from lists).
__global__ __launch_bounds__(TPB)
void k1_scan(const float* __restrict__ logits,
             const float* __restrict__ temps,
             const int* __restrict__ top_ks,
             float* __restrict__ out_probs,
             float* __restrict__ ws_meta,   // [slot][2] {Cy, z}
             unsigned* __restrict__ ws_cut, // [slot]
             unsigned* __restrict__ ws_cnt, // [slot] raw count (overflow visible)
             ull* __restrict__ ws_cand,     // [slot][LCAND]
             int V, int Vq)
{
    const int sblk = blockIdx.x;
    const int b = sblk / SPLIT, s = sblk % SPLIT;
    const int tid = threadIdx.x, lane = tid & 63, w = tid >> 6;
    const int start = s * Vq;
    const int len = min(Vq, V - start);
    const int slot = sblk;
    const float invT = 1.0f / temps[b];
    int K = top_ks[b]; K = max(K, 1); K = min(K, 1024);

    __shared__ unsigned hist[NB];
    __shared__ unsigned uscr[32];
    __shared__ float fred[32];
    __shared__ unsigned cnt;
    __shared__ int bstar;

    if (len <= 0) {
        if (tid == 0) {
            ws_meta[2*slot] = -1e30f; ws_meta[2*slot+1] = 0.0f;
            ws_cut[slot] = 0xFFFFFFFFu; ws_cnt[slot] = 0u;
        }
        return;
    }

    for (int i = tid; i < NB; i += TPB) hist[i] = 0;
    if (tid == 0) { cnt = 0; bstar = 0; }
    __syncthreads();

    const float* __restrict__ row = logits + (size_t)b * V + start;
    const vfloat4* __restrict__ row4 = (const vfloat4*)row;
    const int L4 = len >> 2;

    // ---- presample: first nps elems -> max + histogram ----
    const int nps = min(len, PS);
    float m0 = -1e30f;
    for (int i = tid; i < nps; i += TPB) {
        float lv = row[i];
        m0 = fmaxf(m0, lv);
        atomicAdd(&hist[fkey(lv) >> 21], 1u);
    }
    #pragma unroll
    for (int d = 32; d > 0; d >>= 1) m0 = fmaxf(m0, __shfl_down(m0, d));
    if (lane == 0) fred[w] = m0;
    __syncthreads();
    if (tid == 0) {
        float mm = fred[0];
        for (int j = 1; j < 16; ++j) mm = fmaxf(mm, fred[j]);
        fred[16] = mm;
    }
    __syncthreads();
    const float m0max = fred[16];

    suffix_scan_2048(hist, uscr, tid);
    float sexp = (float)K * (float)nps / (float)V;
    unsigned TGT = (unsigned)(sexp + 6.0f * sqrtf(sexp) + 16.5f);
    if (TGT > (unsigned)nps) TGT = (unsigned)nps;
    for (int e = tid; e < NB; e += TPB) {
        unsigned Se = hist[e];
        unsigned Sn = (e < NB - 1) ? hist[e + 1] : 0u;
        if (Se >= TGT && Sn < TGT) bstar = e;    // unique writer
    }
    __syncthreads();
    const unsigned cutkey = (unsigned)bstar << 21;
    const float cutval = funkey(cutkey);

    // ---- zero epilogue FIRST (nt stores drain while reads stream) ----
    {
        float* __restrict__ orow = out_probs + (size_t)b * V + start;
        vfloat4* __restrict__ orow4 = (vfloat4*)orow;
        const vfloat4 z4 = (vfloat4)0.0f;
        for (int i = tid; i < L4; i += TPB) __builtin_nontemporal_store(z4, &orow4[i]);
        for (int i = (L4 << 2) + tid; i < len; i += TPB) __builtin_nontemporal_store(0.0f, &orow[i]);
    }

    const float ca = invT * L2E;
    const float cb = -m0max * invT * L2E;
    ull* gc = ws_cand + (size_t)slot * LCAND;

    float z0 = 0.0f, z1 = 0.0f, z2 = 0.0f, z3 = 0.0f;

    #define E4(v) (exp2f(fmaf((v)[0], ca, cb)) + exp2f(fmaf((v)[1], ca, cb)) \
                 + exp2f(fmaf((v)[2], ca, cb)) + exp2f(fmaf((v)[3], ca, cb)))
    #define GATHER(v, ii) do {                                                  \
        bool c0 = (v)[0] >= cutval, c1 = (v)[1] >= cutval,                      \
             c2 = (v)[2] >= cutval, c3 = (v)[3] >= cutval;                      \
        if (c0 | c1 | c2 | c3) {                                                \
            int nh = (int)c0 + (int)c1 + (int)c2 + (int)c3;                     \
            unsigned base = atomicAdd(&cnt, (unsigned)nh);                      \
            unsigned bi = (unsigned)(start + ((ii) << 2));                      \
            if (c0) { if (base < LCAND) gc[base] = packkv(fkey((v)[0]), bi+0); base++; } \
            if (c1) { if (base < LCAND) gc[base] = packkv(fkey((v)[1]), bi+1); base++; } \
            if (c2) { if (base < LCAND) gc[base] = packkv(fkey((v)[2]), bi+2); base++; } \
            if (c3) { if (base < LCAND) gc[base] = packkv(fkey((v)[3]), bi+3); base++; } \
        }                                                                       \
    } while (0)

    // ---- main pass: 4 loads in flight, 4 independent accumulators ----
    int i = tid;
    for (; i + 3 * TPB < L4; i += 4 * TPB) {
        vfloat4 va = row4[i];
        vfloat4 vb = row4[i + TPB];
        vfloat4 vc = row4[i + 2 * TPB];
        vfloat4 vd = row4[i + 3 * TPB];
        z0 += E4(va); z1 += E4(vb); z2 += E4(vc); z3 += E4(vd);
        GATHER(va, i); GATHER(vb, i + TPB); GATHER(vc, i + 2 * TPB); GATHER(vd, i + 3 * TPB);
    }
    for (; i < L4; i += TPB) {
        vfloat4 v = row4[i];
        z0 += E4(v);
        GATHER(v, i);
    }
    for (int j = (L4 << 2) + tid; j < len; j += TPB) {
        float lv = row[j];
        z0 += exp2f(fmaf(lv, ca, cb));
        if (lv >= cutval) {
            unsigned base = atomicAdd(&cnt, 1u);
            if (base < LCAND) gc[base] = packkv(fkey(lv), (unsigned)(start + j));
        }
    }
    #undef E4
    #undef GATHER

    float z = (z0 + z1) + (z2 + z3);
    __syncthreads();   // protect fred reuse
    #pragma unroll
    for (int d = 32; d > 0; d >>= 1) z += __shfl_down(z, d);
    if (lane == 0) fred[w] = z;
    __syncthreads();
    if (tid == 0) {
        float zz = 0.0f;
        for (int j = 0; j < 16; ++j) zz += fred[j];
        ws_meta[2*slot + 0] = m0max * invT;   // Cy
        ws_meta[2*slot + 1] = zz;             // sum 2^((x-m0max)*invT*L2E)
        ws_cut[slot] = cutkey;
        ws_cnt[slot] = cnt;
    }
}

// ============================ K2 ============================
// grid = B. Single-pass adaptive threshold + scatter-sort; full-row fallback.
__global__ __launch_bounds__(TPB)
void k2_sample(const float* __restrict__ logits,
               const float* __restrict__ temps,
               const int* __restrict__ top_ks,
               const float* __restrict__ top_ps,
               const float* __restrict__ min_ps,
               const float* __restrict__ uvec,
               const float* __restrict__ ws_meta,
               const unsigned* __restrict__ ws_cut,
               const unsigned* __restrict__ ws_cnt,
               const ull* __restrict__ ws_cand,
               float* __restrict__ out_tok,
               float* __restrict__ out_probs,
               int V)
{
    const int b = blockIdx.x;
    const int tid = threadIdx.x, lane = tid & 63, w = tid >> 6;
    const float invT = 1.0f / temps[b];
    int Korig = top_ks[b]; Korig = max(Korig, 1); Korig = min(Korig, 1024);
    const unsigned Ku = (unsigned)Korig;
    const float top_p = top_ps[b], min_p = min_ps[b], uval = uvec[b];

    // LDS carve
    __shared__ __align__(16) char smem[53504];
    ull*            cand  = (ull*)(smem);                       // [2048] (fb path)
    ull*            cand2 = (ull*)(smem + 16384);               // [2048] sorted dest
    unsigned*       hist  = (unsigned*)(smem + 32768);          // [2049]
    unsigned short* cnts  = (unsigned short*)(smem + 41216);    // [2048]
    float*          sh_p  = (float*)(smem + 45312);             // [1024]
    float*          sh_c  = (float*)(smem + 49408);             // [1024]
    __shared__ unsigned uscr[32];
    __shared__ float fws[32];
    __shared__ unsigned scnt, sh_mk;
    __shared__ int sh_i1, sh_i2;
    __shared__ unsigned sh_u1;

    // ---- combine per-block meta ----
    float Cy[SPLIT], zq[SPLIT];
    unsigned cutq[SPLIT], cntq[SPLIT];
    #pragma unroll
    for (int q = 0; q < SPLIT; ++q) {
        int sl = b * SPLIT + q;
        Cy[q] = ws_meta[2*sl]; zq[q] = ws_meta[2*sl+1];
        cutq[q] = ws_cut[sl]; cntq[q] = ws_cnt[sl];
    }
    float Y = -1e30f;
    #pragma unroll
    for (int q = 0; q < SPLIT; ++q) if (cntq[q] > 0u) Y = fmaxf(Y, Cy[q]);
    float Z = 0.0f;
    #pragma unroll
    for (int q = 0; q < SPLIT; ++q)
        if (cntq[q] > 0u && zq[q] > 0.0f) Z += zq[q] * exp2f((Cy[q] - Y) * L2E);

    bool fb = false;
    unsigned cutmax = 0, mincut = 0xFFFFFFFFu;
    #pragma unroll
    for (int q = 0; q < SPLIT; ++q) {
        if (cntq[q] > (unsigned)LCAND) fb = true;          // list truncated
        if (cntq[q] > 0u) {
            if (!isfinite(zq[q])) fb = true;               // Z overflow -> exact path
            cutmax = max(cutmax, cutq[q]);
            mincut = min(mincut, cutq[q]);
        }
    }
    if (mincut == 0xFFFFFFFFu || !isfinite(Z) || Z <= 0.0f) fb = true;

    unsigned Tkeyb = 0;
    int count = 0, bstar = 0, shift = 0;
    unsigned base = mincut;

    // ---------- fast path: one adaptive histogram over candidate lists ----------
    if (!fb) {
        // pass A: find maxkey (true row max is provably in some list)
        unsigned mk = 0;
        if (tid == 0) sh_mk = 0;
        for (int i = tid; i <= NB; i += TPB) hist[i] = 0;   // incl hist[2048]
        if (tid == 0) { sh_i1 = -1; scnt = 0; }
        __syncthreads();
        #pragma unroll
        for (int q = 0; q < SPLIT; ++q) {
            const ull* gc = ws_cand + (size_t)(b * SPLIT + q) * LCAND;
            int nl = min((int)cntq[q], LCAND);
            for (int i = tid; i < nl; i += TPB)
                mk = max(mk, (unsigned)(gc[i] >> 32));
        }
        #pragma unroll
        for (int d = 32; d > 0; d >>= 1) mk = max(mk, __shfl_down(mk, d));
        if (lane == 0) atomicMax(&sh_mk, mk);
        __syncthreads();
        const unsigned maxkey = sh_mk;
        const unsigned range = maxkey - base;
        while ((range >> shift) > (unsigned)(NB - 1)) shift++;

        // pass B: histogram (lists are L2-resident after pass A)
        #pragma unroll
        for (int q = 0; q < SPLIT; ++q) {
            const ull* gc = ws_cand + (size_t)(b * SPLIT + q) * LCAND;
            int nl = min((int)cntq[q], LCAND);
            for (int i = tid; i < nl; i += TPB)
                atomicAdd(&hist[((unsigned)(gc[i] >> 32) - base) >> shift], 1u);
        }
        __syncthreads();
        unsigned fat = 0;
        for (int i = tid; i < NB; i += TPB) {
            unsigned h = hist[i];
            cnts[i] = (unsigned short)h;
            fat = max(fat, h);
        }
        #pragma unroll
        for (int d = 32; d > 0; d >>= 1) fat = max(fat, __shfl_down(fat, d));
        if (lane == 0) uscr[w] = fat;
        __syncthreads();
        if (tid == 0) {
            unsigned m2 = 0;
            for (int j = 0; j < 16; ++j) m2 = max(m2, uscr[j]);
            uscr[16] = m2;
        }
        __syncthreads();
        if (uscr[16] > 64u) fb = true;                      // fat bin -> fallback
    }
    if (!fb) {
        suffix_scan_2048(hist, uscr, tid);
        for (int e = tid; e < NB; e += TPB) {
            unsigned Se = hist[e], Sn = (e < NB - 1) ? hist[e + 1] : 0u;
            if (Se >= Ku && Sn < Ku) { sh_i1 = e; sh_u1 = Se; }
        }
        __syncthreads();
        if (sh_i1 < 0) fb = true;
        else {
            bstar = sh_i1;
            count = (int)sh_u1;
            Tkeyb = base + ((unsigned)bstar << shift);
            if (Tkeyb < cutmax || count > CAND2) fb = true; // exactness guards
        }
    }
    if (!fb) {
        // scatter directly into sorted-by-bin position
        #pragma unroll
        for (int q = 0; q < SPLIT; ++q) {
            const ull* gc = ws_cand + (size_t)(b * SPLIT + q) * LCAND;
            int nl = min((int)cntq[q], LCAND);
            for (int i = tid; i < nl; i += TPB) {
                ull e = gc[i];
                unsigned k = (unsigned)(e >> 32);
                if (k >= Tkeyb) {
                    unsigned bin = (k - base) >> shift;
                    unsigned pos = atomicAdd(&hist[bin + 1], 1u);  // base S[bin+1]
                    cand2[pos] = e;
                }
            }
        }
        __syncthreads();
        for (int e = bstar + tid; e < NB; e += TPB) {       // fix multi-elem bins
            int c = (int)cnts[e];
            if (c >= 2) {
                int st = (int)hist[e + 1] - c;
                for (int x = 1; x < c; ++x) {
                    ull key = cand2[st + x];
                    int y = x - 1;
                    while (y >= 0 && cand2[st + y] < key) { cand2[st + y + 1] = cand2[st + y]; --y; }
                    cand2[st + y + 1] = key;
                }
            }
        }
        __syncthreads();
    }

    // ---------- slow path: full-row exact recompute (correctness net) ----------
    if (fb) {
        const float* __restrict__ row = logits + (size_t)b * V;
        float m = -1e30f, z = 0.0f;
        for (int i = tid; i < V; i += TPB) {
            float y = row[i] * invT;
            float nm = fmaxf(m, y);
            z = z * exp2f((m - nm) * L2E) + exp2f((y - nm) * L2E);
            m = nm;
        }
        sh_p[tid] = m; sh_c[tid] = z;
        __syncthreads();
        for (int d = TPB >> 1; d > 0; d >>= 1) {
            if (tid < d) {
                float m1 = sh_p[tid], z1 = sh_c[tid];
                float m2 = sh_p[tid + d], z2 = sh_c[tid + d];
                float mm = fmaxf(m1, m2);
                sh_c[tid] = z1 * exp2f((m1 - mm) * L2E) + z2 * exp2f((m2 - mm) * L2E);
                sh_p[tid] = mm;
            }
            __syncthreads();
        }
        Y = sh_p[0]; Z = sh_c[0];
        __syncthreads();
        for (int i = tid; i < NB; i += TPB) hist[i] = 0;
        if (tid == 0) { sh_i1 = 0; sh_i2 = 0; sh_u1 = 0; }
        __syncthreads();
        for (int i = tid; i < V; i += TPB) atomicAdd(&hist[fkey(row[i]) >> 21], 1u);
        __syncthreads();
        suffix_scan_2048(hist, uscr, tid);
        for (int e = tid; e < NB; e += TPB) {
            unsigned Se = hist[e], Sn = (e < NB-1) ? hist[e+1] : 0u;
            if (Se >= Ku && Sn < Ku) { sh_i1 = e; sh_u1 = Sn; }
        }
        __syncthreads();
        int b1 = sh_i1;
        unsigned cab = sh_u1;
        for (int i = tid; i < NB; i += TPB) hist[i] = 0;
        __syncthreads();
        for (int i = tid; i < V; i += TPB) {
            unsigned k = fkey(row[i]);
            if ((int)(k >> 21) == b1) atomicAdd(&hist[(k >> 10) & (NB - 1)], 1u);
        }
        __syncthreads();
        suffix_scan_2048(hist, uscr, tid);
        for (int e = tid; e < NB; e += TPB) {
            unsigned Se = cab + hist[e];
            unsigned Sn = cab + ((e < NB-1) ? hist[e+1] : 0u);
            if (Se >= Ku && Sn < Ku) sh_i2 = e;
        }
        __syncthreads();
        unsigned Tkey = ((unsigned)b1 << 21) | ((unsigned)sh_i2 << 10);
        if (tid == 0) scnt = 0;
        __syncthreads();
        for (int i = tid; i < V; i += TPB) {
            unsigned k = fkey(row[i]);
            if (k >= Tkey) {
                unsigned pos = atomicAdd(&scnt, 1u);
                if (pos < CAND2) cand[pos] = packkv(k, (unsigned)i);
            }
        }
        __syncthreads();
        count = (scnt < (unsigned)CAND2) ? (int)scnt : CAND2;

        int n_sort = 1;
        while (n_sort < count) n_sort <<= 1;
        for (int i = tid; i < n_sort; i += TPB)
            if (i >= count) cand[i] = 0ull;
        __syncthreads();
        for (int kk = 2; kk <= n_sort; kk <<= 1) {
            for (int j = kk >> 1; j > 0; j >>= 1) {
                for (int i = tid; i < n_sort; i += TPB) {
                    int ixj = i ^ j;
                    if (ixj > i) {
                        ull a = cand[i], c = cand[ixj];
                        bool up = (i & kk) == 0;
                        if (up ? (a < c) : (a > c)) { cand[i] = c; cand[ixj] = a; }
                    }
                }
                __syncthreads();
            }
        }
    }

    ull* srt = fb ? cand : cand2;
    int K = min(Korig, count);

    // ---------- probs for top-K prefix, shuffle prefix-sum ----------
    float pv = 0.0f;
    if (tid < K) {
        unsigned k = (unsigned)(srt[tid] >> 32);
        pv = exp2f((funkey(k) * invT - Y) * L2E) / Z;
    }
    float inc = pv;
    #pragma unroll
    for (int d = 1; d < 64; d <<= 1) { float o = __shfl_up(inc, d); if (lane >= d) inc += o; }
    if (lane == 63) fws[w] = inc;
    __syncthreads();
    if (w == 0) {
        float v = (lane < 16) ? fws[lane] : 0.0f;
        float vi = v;
        #pragma unroll
        for (int d = 1; d < 16; d <<= 1) { float o = __shfl_up(vi, d); if (lane >= d) vi += o; }
        if (lane < 16) fws[16 + lane] = vi - v;
    }
    __syncthreads();
    float cum = inc + fws[16 + w];
    sh_p[tid] = pv;
    sh_c[tid] = cum;
    if (tid == 0) sh_i1 = K;
    __syncthreads();

    // top-p (exclusive cumsum BEFORE masking, as reference)
    if (tid < K) {
        float excl = cum - pv;
        if (excl > top_p) atomicMin(&sh_i1, tid);
    }
    __syncthreads();
    int n1 = sh_i1;
    float thr = sh_p[0] * min_p;
    if (tid == 0) sh_i2 = n1;
    __syncthreads();
    if (tid < n1 && sh_p[tid] < thr) atomicMin(&sh_i2, tid);
    __syncthreads();
    int nf = sh_i2;                         // >= 1
    float total = sh_c[nf - 1];

    // ---------- inverse-CDF sample ----------
    int pred = (tid < nf) && ((sh_c[tid] / total) < uval);
    int rank = __syncthreads_count(pred);
    if (rank > nf - 1) rank = nf - 1;
    if (rank < 0) rank = 0;
    if (tid == 0)
        out_tok[b] = (float)(~(unsigned)(srt[rank] & 0xFFFFFFFFull));

    // ---------- scatter survivors (out_probs zeroed by K1) ----------
    if (tid < nf) {
        unsigned idx = ~(unsigned)(srt[tid] & 0xFFFFFFFFull);
        out_probs[(size_t)b * V + idx] = sh_p[tid] / total;
    }
}

extern "C" void kernel_launch(void* const* d_in, const int* in_sizes, int n_in,
                              void* d_out, int out_size, void* d_ws, size_t ws_size,
                              hipStream_t stream) {
    const float* logits = (const float*)d_in[0];
    const float* temps  = (const float*)d_in[1];
    const int*   top_ks = (const int*)d_in[2];
    const float* top_ps = (const float*)d_in[3];
    const float* min_ps = (const float*)d_in[4];
    const float* u      = (const float*)d_in[5];
    const int B = in_sizes[1];
    const int V = in_sizes[0] / B;
    float* out_tok   = (float*)d_out;
    float* out_probs = out_tok + B;

    int Vq = (((V + SPLIT - 1) / SPLIT) + 3) & ~3;   // quarter-row, float4-aligned

    char* ws = (char*)d_ws;
    size_t off = 0;
    auto take = [&](size_t bytes) { char* p = ws + off; off = (off + bytes + 255) & ~(size_t)255; return p; };
    float*    ws_meta = (float*)take((size_t)B * SPLIT * 2 * sizeof(float));
    unsigned* ws_cut  = (unsigned*)take((size_t)B * SPLIT * sizeof(unsigned));
    unsigned* ws_cnt  = (unsigned*)take((size_t)B * SPLIT * sizeof(unsigned));
    ull*      ws_cand = (ull*)take((size_t)B * SPLIT * LCAND * sizeof(ull));
    (void)ws_size;

    k1_scan<<<dim3(SPLIT * B), dim3(TPB), 0, stream>>>(
        logits, temps, top_ks, out_probs, ws_meta, ws_cut, ws_cnt, ws_cand, V, Vq);
    k2_sample<<<dim3(B), dim3(TPB), 0, stream>>>(
        logits, temps, top_ks, top_ps, min_ps, u, ws_meta, ws_cut, ws_cnt, ws_cand,
        out_tok, out_probs, V);
}